// Round 1
// baseline (786.292 us; speedup 1.0000x reference)
//
#include <hip/hip_runtime.h>
#include <math.h>

#define S_LEN 1024
#define NHEAD 8
#define BATCH 8
#define KDIM  64
#define HID   32
#define NT    2048

typedef __attribute__((ext_vector_type(8))) short bf16x8;
typedef __attribute__((ext_vector_type(4))) float f32x4;
typedef unsigned short ushort_t;

__device__ inline ushort_t f2bf(float f) {
  union { float f; unsigned u; } v; v.f = f;
  unsigned u = v.u;
  return (ushort_t)((u + 0x7FFFu + ((u >> 16) & 1u)) >> 16);
}
__device__ inline float bf2f(ushort_t u) {
  union { unsigned x; float f; } v; v.x = ((unsigned)u) << 16; return v.f;
}

__device__ inline float wave_max(float v) {
  #pragma unroll
  for (int off = 32; off > 0; off >>= 1) v = fmaxf(v, __shfl_xor(v, off));
  return v;
}
__device__ inline float wave_sum(float v) {
  #pragma unroll
  for (int off = 32; off > 0; off >>= 1) v += __shfl_xor(v, off);
  return v;
}

// ---------------------------------------------------------------------------
// Kernel 1: FIRE tables. num[h][d]=log1p(c*d), rden[h][i]=1/log1p(c*max(L,i+1)),
// gtab[h][t] = f_theta_h(t/NT) for t=0..NT (the scalar MLP tabulated on [0,1]).
// ---------------------------------------------------------------------------
__global__ void fire_tables(const float* __restrict__ c_raw, const float* __restrict__ Lp,
                            const float* __restrict__ w1, const float* __restrict__ b1,
                            const float* __restrict__ W2, const float* __restrict__ b2,
                            const float* __restrict__ w3, const float* __restrict__ b3,
                            float* __restrict__ num_g, float* __restrict__ rden_g,
                            float* __restrict__ gtab_g) {
  const int h = blockIdx.x;
  const int tid = threadIdx.x;
  const float cr = c_raw[h];
  const float c = (cr > 20.f) ? cr : log1pf(expf(cr));
  const float Lh = Lp[h];
  for (int i = tid; i < S_LEN; i += blockDim.x) {
    num_g[h * S_LEN + i] = log1pf(c * (float)i);
    rden_g[h * S_LEN + i] = 1.0f / log1pf(c * fmaxf(Lh, (float)(i + 1)));
  }
  for (int t = tid; t <= NT; t += blockDim.x) {
    const float x = (float)t * (1.0f / NT);
    float h1[HID];
    #pragma unroll
    for (int j = 0; j < HID; ++j) {
      float v = x * w1[h * HID + j] + b1[h * HID + j];
      h1[j] = 0.5f * v * (1.0f + erff(v * 0.70710678118f));
    }
    float y = b3[h];
    for (int j = 0; j < HID; ++j) {
      float s = b2[h * HID + j];
      const float* w2r = W2 + ((size_t)(h * HID + j)) * HID;
      #pragma unroll
      for (int k = 0; k < HID; ++k) s += w2r[k] * h1[k];
      float g = 0.5f * s * (1.0f + erff(s * 0.70710678118f));
      y += w3[h * HID + j] * g;
    }
    gtab_g[h * (NT + 1) + t] = y;
  }
}

// ---------------------------------------------------------------------------
// Kernel 2: bf16 MFMA GEMM, C = A (MxK,f32) * W^T (W is NxK row-major, f32).
// Block tile 64x64, BK=64, 4 waves; wave w computes rows [16w,16w+16) x 64 cols.
// scatter=1: out is ushort (bf16) in [B][H][S][KD] layout (QKV). scatter=0:
// out is float, plain row-major MxN.
// ---------------------------------------------------------------------------
__global__ __launch_bounds__(256) void gemm_bt(
    const float* __restrict__ A,
    const float* __restrict__ Wa, const float* __restrict__ Wb, const float* __restrict__ Wc,
    void* __restrict__ outQ, void* __restrict__ outK, void* __restrict__ outV,
    int K, int scatter) {
  __shared__ __align__(16) ushort_t sA[64][72];   // +8 pad: 2-way bank alias (free)
  __shared__ __align__(16) ushort_t sB[64][72];
  const int tid = threadIdx.x;
  const int lane = tid & 63;
  const int w = tid >> 6;
  const int quad = lane >> 4;
  const int l16 = lane & 15;
  const int m0 = blockIdx.x * 64;
  const int n0 = blockIdx.y * 64;
  const float* W = (blockIdx.z == 0) ? Wa : (blockIdx.z == 1) ? Wb : Wc;
  void* out = (blockIdx.z == 0) ? outQ : (blockIdx.z == 1) ? outK : outV;

  f32x4 acc[4];
  #pragma unroll
  for (int i = 0; i < 4; ++i) acc[i] = (f32x4)0.0f;

  for (int kt = 0; kt < K; kt += 64) {
    #pragma unroll
    for (int it = 0; it < 4; ++it) {
      int idx = tid + 256 * it;          // 0..1023
      int row = idx >> 4;                // 0..63
      int c4 = (idx & 15) << 2;          // 0..60
      const float4 av = *(const float4*)&A[(size_t)(m0 + row) * K + kt + c4];
      ushort4 ap; ap.x = f2bf(av.x); ap.y = f2bf(av.y); ap.z = f2bf(av.z); ap.w = f2bf(av.w);
      *(ushort4*)&sA[row][c4] = ap;
      const float4 bv = *(const float4*)&W[(size_t)(n0 + row) * K + kt + c4];
      ushort4 bp; bp.x = f2bf(bv.x); bp.y = f2bf(bv.y); bp.z = f2bf(bv.z); bp.w = f2bf(bv.w);
      *(ushort4*)&sB[row][c4] = bp;
    }
    __syncthreads();
    #pragma unroll
    for (int ks = 0; ks < 2; ++ks) {
      bf16x8 af = *(bf16x8*)&sA[w * 16 + l16][ks * 32 + quad * 8];
      #pragma unroll
      for (int nb = 0; nb < 4; ++nb) {
        bf16x8 bf = *(bf16x8*)&sB[nb * 16 + l16][ks * 32 + quad * 8];
        acc[nb] = __builtin_amdgcn_mfma_f32_16x16x32_bf16(af, bf, acc[nb], 0, 0, 0);
      }
    }
    __syncthreads();
  }
  // Epilogue. D layout: col = lane&15, row = quad*4 + reg (guide-verified m89/m91).
  #pragma unroll
  for (int nb = 0; nb < 4; ++nb) {
    #pragma unroll
    for (int r = 0; r < 4; ++r) {
      int m = m0 + w * 16 + quad * 4 + r;
      int n = n0 + nb * 16 + l16;
      float vout = acc[nb][r];
      if (scatter) {
        int b = m >> 10, s = m & 1023, hh = n >> 6, kd = n & 63;
        ((ushort_t*)out)[(((size_t)(b * NHEAD + hh)) * S_LEN + s) * KDIM + kd] = f2bf(vout);
      } else {
        ((float*)out)[(size_t)m * 512 + n] = vout;
      }
    }
  }
}

// ---------------------------------------------------------------------------
// Kernel 3: causal flash attention with FIRE bias via table lookup.
// Block = 256 thr (4 waves) handles 8 consecutive query rows of one (b,h);
// each wave owns 2 rows. K/V tiles (64 keys) staged in LDS, pitch 65.
// ---------------------------------------------------------------------------
__global__ __launch_bounds__(256) void fire_attn(
    const ushort_t* __restrict__ Qg, const ushort_t* __restrict__ Kg, const ushort_t* __restrict__ Vg,
    const float* __restrict__ num_g, const float* __restrict__ rden_g,
    const float* __restrict__ gtab_g, float* __restrict__ O) {
  __shared__ float Ks[64][65];
  __shared__ float Vs[64][65];
  __shared__ float num_s[S_LEN];
  __shared__ float gtab_s[NT + 1];
  __shared__ float qs[8][64];
  __shared__ float ps[8][64];

  const int tid = threadIdx.x;
  const int lane = tid & 63;
  const int w = tid >> 6;
  const int bh = blockIdx.y;            // b*8 + h
  const int h = bh & (NHEAD - 1);
  const int r0 = blockIdx.x * 8;

  for (int i = tid; i < S_LEN; i += 256) num_s[i] = num_g[h * S_LEN + i];
  for (int i = tid; i <= NT; i += 256) gtab_s[i] = gtab_g[h * (NT + 1) + i];
  {
    const size_t qbase = ((size_t)bh * S_LEN + r0) * KDIM;
    for (int i = tid; i < 512; i += 256) qs[i >> 6][i & 63] = bf2f(Qg[qbase + i]);
  }
  __syncthreads();

  const int wr = w * 2;
  const int i0 = r0 + wr, i1 = i0 + 1;
  const float rden0 = rden_g[h * S_LEN + i0];
  const float rden1 = rden_g[h * S_LEN + i1];

  float m0 = -INFINITY, m1 = -INFINITY;
  float l0 = 0.f, l1 = 0.f, o0 = 0.f, o1 = 0.f;

  const int T = r0 / 64 + 1;   // r0%64 <= 56 so rows r0..r0+7 end in tile r0/64
  for (int t = 0; t < T; ++t) {
    const size_t base = ((size_t)bh * S_LEN + t * 64) * KDIM;
    for (int i = tid * 4; i < 4096; i += 1024) {
      int j = i >> 6, kd = i & 63;
      ushort4 kv4 = *(const ushort4*)&Kg[base + i];
      Ks[j][kd + 0] = bf2f(kv4.x); Ks[j][kd + 1] = bf2f(kv4.y);
      Ks[j][kd + 2] = bf2f(kv4.z); Ks[j][kd + 3] = bf2f(kv4.w);
      ushort4 vv4 = *(const ushort4*)&Vg[base + i];
      Vs[j][kd + 0] = bf2f(vv4.x); Vs[j][kd + 1] = bf2f(vv4.y);
      Vs[j][kd + 2] = bf2f(vv4.z); Vs[j][kd + 3] = bf2f(vv4.w);
    }
    __syncthreads();

    const int j = t * 64 + lane;
    float d0 = 0.f, d1 = 0.f;
    #pragma unroll 8
    for (int kd = 0; kd < 64; ++kd) {
      float kv = Ks[lane][kd];
      d0 += qs[wr][kd] * kv;
      d1 += qs[wr + 1][kd] * kv;
    }
    const bool v0 = (j <= i0);
    const bool v1 = (j <= i1);
    float lg0, lg1;
    {
      int dd = i0 - j; if (dd < 0) dd = 0;
      float x = num_s[dd] * rden0;
      float tf = x * (float)NT;
      int it = (int)tf; it = it < (NT - 1) ? it : (NT - 1);
      float fr = tf - (float)it;
      float ga = gtab_s[it];
      float bias = ga + (gtab_s[it + 1] - ga) * fr;
      lg0 = v0 ? 0.125f * d0 + bias : -INFINITY;
    }
    {
      int dd = i1 - j; if (dd < 0) dd = 0;
      float x = num_s[dd] * rden1;
      float tf = x * (float)NT;
      int it = (int)tf; it = it < (NT - 1) ? it : (NT - 1);
      float fr = tf - (float)it;
      float ga = gtab_s[it];
      float bias = ga + (gtab_s[it + 1] - ga) * fr;
      lg1 = v1 ? 0.125f * d1 + bias : -INFINITY;
    }
    // online softmax (per wave; each row always has >=1 valid key per tile)
    float nm0 = fmaxf(m0, wave_max(lg0));
    float nm1 = fmaxf(m1, wave_max(lg1));
    float a0 = __expf(m0 - nm0);
    float a1 = __expf(m1 - nm1);
    float p0 = v0 ? __expf(lg0 - nm0) : 0.f;
    float p1 = v1 ? __expf(lg1 - nm1) : 0.f;
    l0 = l0 * a0 + wave_sum(p0);
    l1 = l1 * a1 + wave_sum(p1);
    m0 = nm0; m1 = nm1;
    ps[wr][lane] = p0;
    ps[wr + 1][lane] = p1;
    // phase 2: lane = kd. ps written/read by same wave (compiler inserts lgkmcnt).
    o0 *= a0; o1 *= a1;
    #pragma unroll 8
    for (int jj = 0; jj < 64; ++jj) {
      float vv = Vs[jj][lane];
      o0 += ps[wr][jj] * vv;
      o1 += ps[wr + 1][jj] * vv;
    }
    __syncthreads();
  }
  const int b = bh >> 3;
  const size_t ob = ((size_t)b * S_LEN + i0) * 512 + h * KDIM + lane;
  O[ob] = o0 / l0;
  O[ob + 512] = o1 / l1;   // row i1 = i0+1
}

// ---------------------------------------------------------------------------
extern "C" void kernel_launch(void* const* d_in, const int* in_sizes, int n_in,
                              void* d_out, int out_size, void* d_ws, size_t ws_size,
                              hipStream_t stream) {
  const float* src   = (const float*)d_in[0];
  const float* Wq    = (const float*)d_in[1];
  const float* Wk    = (const float*)d_in[2];
  const float* Wv    = (const float*)d_in[3];
  const float* c_raw = (const float*)d_in[4];
  const float* Lp    = (const float*)d_in[5];
  const float* w1    = (const float*)d_in[6];
  const float* b1    = (const float*)d_in[7];
  const float* W2    = (const float*)d_in[8];
  const float* b2    = (const float*)d_in[9];
  const float* w3    = (const float*)d_in[10];
  const float* b3    = (const float*)d_in[11];
  const float* Wo    = (const float*)d_in[12];
  float* outp = (float*)d_out;

  const size_t QKV_ELEMS = (size_t)BATCH * NHEAD * S_LEN * KDIM;  // 4 Mi
  // ws layout: Q,K,V as bf16 (ushort), O as f32, then tables.
  ushort_t* Qb = (ushort_t*)d_ws;
  ushort_t* Kb = Qb + QKV_ELEMS;
  ushort_t* Vb = Kb + QKV_ELEMS;
  float* Ob    = (float*)(Vb + QKV_ELEMS);
  float* numb  = Ob + (size_t)BATCH * S_LEN * 512;
  float* rdenb = numb + NHEAD * S_LEN;
  float* gtabb = rdenb + NHEAD * S_LEN;

  hipLaunchKernelGGL(fire_tables, dim3(NHEAD), dim3(256), 0, stream,
                     c_raw, Lp, w1, b1, W2, b2, w3, b3, numb, rdenb, gtabb);
  hipLaunchKernelGGL(gemm_bt, dim3(128, 8, 3), dim3(256), 0, stream,
                     src, Wq, Wk, Wv, (void*)Qb, (void*)Kb, (void*)Vb, 512, 1);
  hipLaunchKernelGGL(fire_attn, dim3(128, 64), dim3(256), 0, stream,
                     Qb, Kb, Vb, numb, rdenb, gtabb, Ob);
  hipLaunchKernelGGL(gemm_bt, dim3(128, 8, 1), dim3(256), 0, stream,
                     Ob, Wo, Wo, Wo, (void*)outp, (void*)outp, (void*)outp, 512, 0);
}

// Round 2
// 302.717 us; speedup vs baseline: 2.5974x; 2.5974x over previous
//
#include <hip/hip_runtime.h>
#include <math.h>

#define S_LEN 1024
#define NHEAD 8
#define BATCH 8
#define KDIM  64
#define HID   32
#define NT    2048

typedef __attribute__((ext_vector_type(8))) short bf16x8;
typedef __attribute__((ext_vector_type(4))) float f32x4;
typedef unsigned short ushort_t;

__device__ inline ushort_t f2bf(float f) {
  union { float f; unsigned u; } v; v.f = f;
  unsigned u = v.u;
  return (ushort_t)((u + 0x7FFFu + ((u >> 16) & 1u)) >> 16);
}
__device__ inline float bf2f(ushort_t u) {
  union { unsigned x; float f; } v; v.x = ((unsigned)u) << 16; return v.f;
}

// ---------------------------------------------------------------------------
// Kernel 1: FIRE tables. num[h][d]=log1p(c*d), rden[h][i]=1/log1p(c*max(L,i+1)),
// gtab[h][t] = f_theta_h(t/NT) for t=0..NT. Spread over grid.y for parallelism.
// ---------------------------------------------------------------------------
__global__ void fire_tables(const float* __restrict__ c_raw, const float* __restrict__ Lp,
                            const float* __restrict__ w1, const float* __restrict__ b1,
                            const float* __restrict__ W2, const float* __restrict__ b2,
                            const float* __restrict__ w3, const float* __restrict__ b3,
                            float* __restrict__ num_g, float* __restrict__ rden_g,
                            float* __restrict__ gtab_g) {
  const int h = blockIdx.x;
  const int tid0 = blockIdx.y * 256 + threadIdx.x;   // 0..2047
  const float cr = c_raw[h];
  const float c = (cr > 20.f) ? cr : log1pf(expf(cr));
  const float Lh = Lp[h];
  for (int i = tid0; i < S_LEN; i += 2048) {
    num_g[h * S_LEN + i] = log1pf(c * (float)i);
    rden_g[h * S_LEN + i] = 1.0f / log1pf(c * fmaxf(Lh, (float)(i + 1)));
  }
  for (int t = tid0; t <= NT; t += 2048) {
    const float x = (float)t * (1.0f / NT);
    float h1[HID];
    #pragma unroll
    for (int j = 0; j < HID; ++j) {
      float v = x * w1[h * HID + j] + b1[h * HID + j];
      h1[j] = 0.5f * v * (1.0f + erff(v * 0.70710678118f));
    }
    float y = b3[h];
    for (int j = 0; j < HID; ++j) {
      float s = b2[h * HID + j];
      const float* w2r = W2 + ((size_t)(h * HID + j)) * HID;
      #pragma unroll
      for (int k = 0; k < HID; ++k) s += w2r[k] * h1[k];
      float g = 0.5f * s * (1.0f + erff(s * 0.70710678118f));
      y += w3[h * HID + j] * g;
    }
    gtab_g[h * (NT + 1) + t] = y;
  }
}

// ---------------------------------------------------------------------------
// Kernel 1b: materialize bias[h][i][j] (bf16) = g_h(num[i-j]*rden[i]), d<=0 -> g(0).
// Batch-independent, 16.8 MB, L3-resident. One block per (h,i) row.
// ---------------------------------------------------------------------------
__global__ __launch_bounds__(256) void fire_bias(
    const float* __restrict__ num_g, const float* __restrict__ rden_g,
    const float* __restrict__ gtab_g, ushort_t* __restrict__ biasg) {
  __shared__ float gtab_s[NT + 1];
  __shared__ float num_s[S_LEN];
  const int tid = threadIdx.x;
  const int h = blockIdx.x >> 10;
  const int i = blockIdx.x & 1023;
  for (int t = tid; t <= NT; t += 256) gtab_s[t] = gtab_g[h * (NT + 1) + t];
  for (int t = tid; t < S_LEN; t += 256) num_s[t] = num_g[h * S_LEN + t];
  __syncthreads();
  const float rden = rden_g[h * S_LEN + i];
  const int j0 = tid * 4;
  ushort4 outp;
  #pragma unroll
  for (int c = 0; c < 4; ++c) {
    int j = j0 + c;
    int d = i - j; if (d < 0) d = 0;
    float x = num_s[d] * rden;           // in [0,1)
    float tf = x * (float)NT;
    int it = (int)tf; it = it < (NT - 1) ? it : (NT - 1);
    float fr = tf - (float)it;
    float ga = gtab_s[it];
    float b = ga + (gtab_s[it + 1] - ga) * fr;
    ((ushort_t*)&outp)[c] = f2bf(b);
  }
  *(ushort4*)&biasg[((size_t)(h * S_LEN + i)) * S_LEN + j0] = outp;
}

// ---------------------------------------------------------------------------
// Kernel 2: bf16 MFMA GEMM, C = A (MxK,f32) * W^T (N x K, f32). 64x64 tile.
// scatter=1: out bf16 [B][H][S][KD]; scatter=0: out f32 row-major Mx512.
// ---------------------------------------------------------------------------
__global__ __launch_bounds__(256) void gemm_bt(
    const float* __restrict__ A,
    const float* __restrict__ Wa, const float* __restrict__ Wb, const float* __restrict__ Wc,
    void* __restrict__ outQ, void* __restrict__ outK, void* __restrict__ outV,
    int K, int scatter) {
  __shared__ __align__(16) ushort_t sA[64][72];
  __shared__ __align__(16) ushort_t sB[64][72];
  const int tid = threadIdx.x;
  const int lane = tid & 63;
  const int w = tid >> 6;
  const int quad = lane >> 4;
  const int l16 = lane & 15;
  const int m0 = blockIdx.x * 64;
  const int n0 = blockIdx.y * 64;
  const float* W = (blockIdx.z == 0) ? Wa : (blockIdx.z == 1) ? Wb : Wc;
  void* out = (blockIdx.z == 0) ? outQ : (blockIdx.z == 1) ? outK : outV;

  f32x4 acc[4];
  #pragma unroll
  for (int i = 0; i < 4; ++i) acc[i] = (f32x4)0.0f;

  for (int kt = 0; kt < K; kt += 64) {
    #pragma unroll
    for (int it = 0; it < 4; ++it) {
      int idx = tid + 256 * it;
      int row = idx >> 4;
      int c4 = (idx & 15) << 2;
      const float4 av = *(const float4*)&A[(size_t)(m0 + row) * K + kt + c4];
      ushort4 ap; ap.x = f2bf(av.x); ap.y = f2bf(av.y); ap.z = f2bf(av.z); ap.w = f2bf(av.w);
      *(ushort4*)&sA[row][c4] = ap;
      const float4 bv = *(const float4*)&W[(size_t)(n0 + row) * K + kt + c4];
      ushort4 bp; bp.x = f2bf(bv.x); bp.y = f2bf(bv.y); bp.z = f2bf(bv.z); bp.w = f2bf(bv.w);
      *(ushort4*)&sB[row][c4] = bp;
    }
    __syncthreads();
    #pragma unroll
    for (int ks = 0; ks < 2; ++ks) {
      bf16x8 af = *(bf16x8*)&sA[w * 16 + l16][ks * 32 + quad * 8];
      #pragma unroll
      for (int nb = 0; nb < 4; ++nb) {
        bf16x8 bf = *(bf16x8*)&sB[nb * 16 + l16][ks * 32 + quad * 8];
        acc[nb] = __builtin_amdgcn_mfma_f32_16x16x32_bf16(af, bf, acc[nb], 0, 0, 0);
      }
    }
    __syncthreads();
  }
  #pragma unroll
  for (int nb = 0; nb < 4; ++nb) {
    #pragma unroll
    for (int r = 0; r < 4; ++r) {
      int m = m0 + w * 16 + quad * 4 + r;
      int n = n0 + nb * 16 + l16;
      float vout = acc[nb][r];
      if (scatter) {
        int b = m >> 10, s = m & 1023, hh = n >> 6, kd = n & 63;
        ((ushort_t*)out)[(((size_t)(b * NHEAD + hh)) * S_LEN + s) * KDIM + kd] = f2bf(vout);
      } else {
        ((float*)out)[(size_t)m * 512 + n] = vout;
      }
    }
  }
}

// ---------------------------------------------------------------------------
// Kernel 3: MFMA causal flash attention with precomputed bias matrix.
// Block = (b,h, 64-row Q-tile), 4 waves x 16 rows. K-tile = 64 keys.
// QK^T and PV via mfma_f32_16x16x32_bf16; P transposed C->A layout via LDS.
// ---------------------------------------------------------------------------
__global__ __launch_bounds__(256) void fire_attn_mfma(
    const ushort_t* __restrict__ Qg, const ushort_t* __restrict__ Kg,
    const ushort_t* __restrict__ Vg, const ushort_t* __restrict__ biasg,
    float* __restrict__ O) {
  __shared__ __align__(16) ushort_t Qs[64][72];
  __shared__ __align__(16) ushort_t Ks[64][72];
  __shared__ __align__(16) ushort_t Vt[64][72];   // [kd][j] (V transposed)
  __shared__ __align__(16) ushort_t Ps[64][72];   // per-wave 16-row strips

  const int tid = threadIdx.x;
  const int lane = tid & 63;
  const int w = tid >> 6;
  const int quad = lane >> 4;
  const int l16 = lane & 15;
  const int bh = blockIdx.y;             // b*8 + h
  const int h = bh & (NHEAD - 1);
  const int b = bh >> 3;
  const int qt = 15 - blockIdx.x;        // heavy tiles dispatch first

  // stage Q tile (bf16 passthrough)
  {
    const size_t qbase = ((size_t)bh * S_LEN + qt * 64) * KDIM;
    #pragma unroll
    for (int i = tid * 4; i < 4096; i += 1024) {
      int row = i >> 6, c = i & 63;
      *(ushort4*)&Qs[row][c] = *(const ushort4*)&Qg[qbase + i];
    }
  }

  f32x4 o[4];
  #pragma unroll
  for (int nb = 0; nb < 4; ++nb) o[nb] = (f32x4)0.0f;
  float m[4], l[4];
  #pragma unroll
  for (int r = 0; r < 4; ++r) { m[r] = -INFINITY; l[r] = 0.f; }

  const int i0loc = w * 16 + quad * 4;             // local row of reg r=0
  const int i0 = qt * 64 + i0loc;                  // global row
  const ushort_t* bias_row = biasg + ((size_t)(h * S_LEN + i0)) * S_LEN;

  for (int t = 0; t <= qt; ++t) {
    const size_t base = ((size_t)bh * S_LEN + t * 64) * KDIM;
    __syncthreads();   // protect Ks/Vt from previous iteration's readers
    #pragma unroll
    for (int i = tid * 4; i < 4096; i += 1024) {
      int j = i >> 6, kd0 = i & 63;
      *(ushort4*)&Ks[j][kd0] = *(const ushort4*)&Kg[base + i];
      ushort4 vv = *(const ushort4*)&Vg[base + i];
      Vt[kd0 + 0][j] = vv.x; Vt[kd0 + 1][j] = vv.y;
      Vt[kd0 + 2][j] = vv.z; Vt[kd0 + 3][j] = vv.w;
    }
    __syncthreads();

    // ---- S = Q K^T  (16 rows x 64 keys per wave)
    f32x4 s[4];
    #pragma unroll
    for (int nb = 0; nb < 4; ++nb) s[nb] = (f32x4)0.0f;
    #pragma unroll
    for (int ks = 0; ks < 2; ++ks) {
      bf16x8 aq = *(bf16x8*)&Qs[w * 16 + l16][ks * 32 + quad * 8];
      #pragma unroll
      for (int nb = 0; nb < 4; ++nb) {
        bf16x8 bk = *(bf16x8*)&Ks[nb * 16 + l16][ks * 32 + quad * 8];
        s[nb] = __builtin_amdgcn_mfma_f32_16x16x32_bf16(aq, bk, s[nb], 0, 0, 0);
      }
    }

    // ---- logits = s/8 + bias; causal mask on diagonal tile
    const ushort_t* bp = bias_row + t * 64;
    #pragma unroll
    for (int nb = 0; nb < 4; ++nb) {
      #pragma unroll
      for (int r = 0; r < 4; ++r) {
        float bias = bf2f(bp[(size_t)r * S_LEN + nb * 16 + l16]);
        float v = 0.125f * s[nb][r] + bias;
        if (t == qt) {
          bool valid = (nb * 16 + l16) <= (i0loc + r);
          v = valid ? v : -INFINITY;
        }
        s[nb][r] = v;
      }
    }

    // ---- online softmax (rows quad*4+r; reduce over 4 regs then 16 lanes)
    float alpha[4];
    #pragma unroll
    for (int r = 0; r < 4; ++r) {
      float rm = fmaxf(fmaxf(s[0][r], s[1][r]), fmaxf(s[2][r], s[3][r]));
      #pragma unroll
      for (int off = 1; off < 16; off <<= 1) rm = fmaxf(rm, __shfl_xor(rm, off));
      float nm = fmaxf(m[r], rm);
      alpha[r] = __expf(m[r] - nm);
      m[r] = nm;
    }
    #pragma unroll
    for (int nb = 0; nb < 4; ++nb)
      #pragma unroll
      for (int r = 0; r < 4; ++r)
        s[nb][r] = __expf(s[nb][r] - m[r]);   // masked entries -> exp(-inf)=0
    #pragma unroll
    for (int r = 0; r < 4; ++r) {
      float rs = s[0][r] + s[1][r] + s[2][r] + s[3][r];
      #pragma unroll
      for (int off = 1; off < 16; off <<= 1) rs += __shfl_xor(rs, off);
      l[r] = l[r] * alpha[r] + rs;
    }

    // ---- P (C-layout) -> LDS -> A-layout for PV; wave-private strip
    #pragma unroll
    for (int nb = 0; nb < 4; ++nb)
      #pragma unroll
      for (int r = 0; r < 4; ++r)
        Ps[i0loc + r][nb * 16 + l16] = f2bf(s[nb][r]);

    #pragma unroll
    for (int nb = 0; nb < 4; ++nb) {
      f32x4 ov = o[nb];
      #pragma unroll
      for (int r = 0; r < 4; ++r) ov[r] *= alpha[r];
      o[nb] = ov;
    }
    #pragma unroll
    for (int ks = 0; ks < 2; ++ks) {
      bf16x8 ap = *(bf16x8*)&Ps[w * 16 + l16][ks * 32 + quad * 8];
      #pragma unroll
      for (int nb = 0; nb < 4; ++nb) {
        bf16x8 bv = *(bf16x8*)&Vt[nb * 16 + l16][ks * 32 + quad * 8];
        o[nb] = __builtin_amdgcn_mfma_f32_16x16x32_bf16(ap, bv, o[nb], 0, 0, 0);
      }
    }
  }

  // ---- epilogue: O[b][i][h*64+kd] = o / l
  #pragma unroll
  for (int r = 0; r < 4; ++r) {
    float rl = 1.0f / l[r];
    size_t ob = ((size_t)(b * S_LEN + i0 + r)) * 512 + h * KDIM;
    #pragma unroll
    for (int nb = 0; nb < 4; ++nb)
      O[ob + nb * 16 + l16] = o[nb][r] * rl;
  }
}

// ---------------------------------------------------------------------------
extern "C" void kernel_launch(void* const* d_in, const int* in_sizes, int n_in,
                              void* d_out, int out_size, void* d_ws, size_t ws_size,
                              hipStream_t stream) {
  const float* src   = (const float*)d_in[0];
  const float* Wq    = (const float*)d_in[1];
  const float* Wk    = (const float*)d_in[2];
  const float* Wv    = (const float*)d_in[3];
  const float* c_raw = (const float*)d_in[4];
  const float* Lp    = (const float*)d_in[5];
  const float* w1    = (const float*)d_in[6];
  const float* b1    = (const float*)d_in[7];
  const float* W2    = (const float*)d_in[8];
  const float* b2    = (const float*)d_in[9];
  const float* w3    = (const float*)d_in[10];
  const float* b3    = (const float*)d_in[11];
  const float* Wo    = (const float*)d_in[12];
  float* outp = (float*)d_out;

  const size_t QKV_ELEMS = (size_t)BATCH * NHEAD * S_LEN * KDIM;  // 4 Mi
  ushort_t* Qb = (ushort_t*)d_ws;
  ushort_t* Kb = Qb + QKV_ELEMS;
  ushort_t* Vb = Kb + QKV_ELEMS;
  float* Ob    = (float*)(Vb + QKV_ELEMS);
  float* numb  = Ob + (size_t)BATCH * S_LEN * 512;
  float* rdenb = numb + NHEAD * S_LEN;
  float* gtabb = rdenb + NHEAD * S_LEN;
  ushort_t* biasb = (ushort_t*)(gtabb + NHEAD * (NT + 1));   // [H][S][S] bf16

  hipLaunchKernelGGL(fire_tables, dim3(NHEAD, 8), dim3(256), 0, stream,
                     c_raw, Lp, w1, b1, W2, b2, w3, b3, numb, rdenb, gtabb);
  hipLaunchKernelGGL(fire_bias, dim3(NHEAD * S_LEN), dim3(256), 0, stream,
                     numb, rdenb, gtabb, biasb);
  hipLaunchKernelGGL(gemm_bt, dim3(128, 8, 3), dim3(256), 0, stream,
                     src, Wq, Wk, Wv, (void*)Qb, (void*)Kb, (void*)Vb, 512, 1);
  hipLaunchKernelGGL(fire_attn_mfma, dim3(16, 64), dim3(256), 0, stream,
                     Qb, Kb, Vb, biasb, Ob);
  hipLaunchKernelGGL(gemm_bt, dim3(128, 8, 1), dim3(256), 0, stream,
                     Ob, Wo, Wo, Wo, (void*)outp, (void*)outp, (void*)outp, 512, 0);
}

// Round 3
// 235.857 us; speedup vs baseline: 3.3338x; 1.2835x over previous
//
#include <hip/hip_runtime.h>
#include <math.h>

#define S_LEN 1024
#define NHEAD 8
#define BATCH 8
#define KDIM  64
#define HID   32
#define NT    2048
#define TRI(q) ((q) * ((q) + 1) / 2)

typedef __attribute__((ext_vector_type(8))) short bf16x8;
typedef __attribute__((ext_vector_type(4))) float f32x4;
typedef unsigned short ushort_t;

__device__ inline ushort_t f2bf(float f) {
  union { float f; unsigned u; } v; v.f = f;
  unsigned u = v.u;
  return (ushort_t)((u + 0x7FFFu + ((u >> 16) & 1u)) >> 16);
}
__device__ inline float bf2f(ushort_t u) {
  union { unsigned x; float f; } v; v.x = ((unsigned)u) << 16; return v.f;
}

// ---------------------------------------------------------------------------
// Kernel 0: f32 -> bf16 pre-convert (src + 4 weights; Wq scaled by 0.125).
// ---------------------------------------------------------------------------
__global__ __launch_bounds__(256) void to_bf16(
    const float* __restrict__ s, const float* __restrict__ wq,
    const float* __restrict__ wk, const float* __restrict__ wv,
    const float* __restrict__ wo,
    ushort_t* __restrict__ sb, ushort_t* __restrict__ wqb,
    ushort_t* __restrict__ wkb, ushort_t* __restrict__ wvb,
    ushort_t* __restrict__ wob) {
  const int y = blockIdx.y;
  const float* src; ushort_t* dst; int n; float scale = 1.0f;
  if (y == 0)      { src = s;  dst = sb;  n = 4194304; }
  else if (y == 1) { src = wq; dst = wqb; n = 262144; scale = 0.125f; }
  else if (y == 2) { src = wk; dst = wkb; n = 262144; }
  else if (y == 3) { src = wv; dst = wvb; n = 262144; }
  else             { src = wo; dst = wob; n = 262144; }
  const int i = (blockIdx.x * 256 + threadIdx.x) * 4;
  if (i < n) {
    float4 v = *(const float4*)&src[i];
    ushort4 o;
    o.x = f2bf(v.x * scale); o.y = f2bf(v.y * scale);
    o.z = f2bf(v.z * scale); o.w = f2bf(v.w * scale);
    *(ushort4*)&dst[i] = o;
  }
}

// ---------------------------------------------------------------------------
// Kernel 1: FIRE tables.
// ---------------------------------------------------------------------------
__global__ void fire_tables(const float* __restrict__ c_raw, const float* __restrict__ Lp,
                            const float* __restrict__ w1, const float* __restrict__ b1,
                            const float* __restrict__ W2, const float* __restrict__ b2,
                            const float* __restrict__ w3, const float* __restrict__ b3,
                            float* __restrict__ num_g, float* __restrict__ rden_g,
                            float* __restrict__ gtab_g) {
  const int h = blockIdx.x;
  const int tid0 = blockIdx.y * 256 + threadIdx.x;   // 0..2047
  const float cr = c_raw[h];
  const float c = (cr > 20.f) ? cr : log1pf(expf(cr));
  const float Lh = Lp[h];
  for (int i = tid0; i < S_LEN; i += 2048) {
    num_g[h * S_LEN + i] = log1pf(c * (float)i);
    rden_g[h * S_LEN + i] = 1.0f / log1pf(c * fmaxf(Lh, (float)(i + 1)));
  }
  for (int t = tid0; t <= NT; t += 2048) {
    const float x = (float)t * (1.0f / NT);
    float h1[HID];
    #pragma unroll
    for (int j = 0; j < HID; ++j) {
      float v = x * w1[h * HID + j] + b1[h * HID + j];
      h1[j] = 0.5f * v * (1.0f + erff(v * 0.70710678118f));
    }
    float y = b3[h];
    for (int j = 0; j < HID; ++j) {
      float s = b2[h * HID + j];
      const float* w2r = W2 + ((size_t)(h * HID + j)) * HID;
      #pragma unroll
      for (int k = 0; k < HID; ++k) s += w2r[k] * h1[k];
      float g = 0.5f * s * (1.0f + erff(s * 0.70710678118f));
      y += w3[h * HID + j] * g;
    }
    gtab_g[h * (NT + 1) + t] = y;
  }
}

// ---------------------------------------------------------------------------
// Kernel 1b: bias pre-arranged in MFMA fragment order, causal -inf baked in.
// biaspre[h][TRI(qt)+t][tid][16 bf16]; value v = nb*4+r maps to
// row i = qt*64 + (tid>>6)*16 + ((tid&63)>>4)*4 + r, col j = t*64 + nb*16 + (tid&15).
// ---------------------------------------------------------------------------
__global__ __launch_bounds__(256) void fire_bias_pre(
    const float* __restrict__ num_g, const float* __restrict__ rden_g,
    const float* __restrict__ gtab_g, ushort_t* __restrict__ biaspre) {
  __shared__ float gtab_s[NT + 1];
  __shared__ float num_s[S_LEN];
  __shared__ float rden_s[64];
  const int tid = threadIdx.x;
  const int h = blockIdx.y;
  const int tileIdx = blockIdx.x;          // 0..135
  int qt = 0;
  while (TRI(qt + 1) <= tileIdx) ++qt;
  const int t = tileIdx - TRI(qt);
  for (int i = tid; i <= NT; i += 256) gtab_s[i] = gtab_g[h * (NT + 1) + i];
  for (int i = tid; i < S_LEN; i += 256) num_s[i] = num_g[h * S_LEN + i];
  if (tid < 64) rden_s[tid] = rden_g[h * S_LEN + qt * 64 + tid];
  __syncthreads();
  const int lane = tid & 63, w = tid >> 6, quad = lane >> 4, l16 = lane & 15;
  ushort_t vals[16];
  #pragma unroll
  for (int nb = 0; nb < 4; ++nb) {
    #pragma unroll
    for (int r = 0; r < 4; ++r) {
      const int iloc = w * 16 + quad * 4 + r;
      const int i = qt * 64 + iloc;
      const int j = t * 64 + nb * 16 + l16;
      ushort_t out;
      if (j > i) {
        out = 0xFF80;  // bf16 -inf (causal mask baked in)
      } else {
        const int d = i - j;                  // >= 0; d==0 -> num=0 -> g(0)
        float x = num_s[d] * rden_s[iloc];    // in [0,1)
        float tf = x * (float)NT;
        int it = (int)tf; it = it < (NT - 1) ? it : (NT - 1);
        float fr = tf - (float)it;
        float ga = gtab_s[it];
        out = f2bf(ga + (gtab_s[it + 1] - ga) * fr);
      }
      vals[nb * 4 + r] = out;
    }
  }
  ushort_t* dst = &biaspre[(((size_t)h * 136 + tileIdx) * 256 + tid) * 16];
  uint4 lo, hi;
  #pragma unroll
  for (int v = 0; v < 8; ++v) { ((ushort_t*)&lo)[v] = vals[v]; ((ushort_t*)&hi)[v] = vals[v + 8]; }
  *(uint4*)dst = lo;
  *(uint4*)(dst + 8) = hi;
}

// ---------------------------------------------------------------------------
// Kernel 2: all-bf16 MFMA GEMM, C = A (Mx512 bf16) * W^T (512x512 bf16, NxK).
// 128x128 tile, BK=64, 4 waves x (32 rows x 128 cols).
// scatter=1: out bf16 [B][H][S][KD]; scatter=0: out f32 row-major Mx512.
// ---------------------------------------------------------------------------
__global__ __launch_bounds__(256) void gemm_bf16(
    const ushort_t* __restrict__ A,
    const ushort_t* __restrict__ W0, const ushort_t* __restrict__ W1,
    const ushort_t* __restrict__ W2w,
    void* __restrict__ out0, void* __restrict__ out1, void* __restrict__ out2,
    int scatter) {
  __shared__ __align__(16) ushort_t sA[128][72];
  __shared__ __align__(16) ushort_t sB[128][72];
  const int tid = threadIdx.x;
  const int lane = tid & 63;
  const int w = tid >> 6;
  const int quad = lane >> 4;
  const int l16 = lane & 15;
  const int m0 = blockIdx.x * 128;
  const int n0 = blockIdx.y * 128;
  const ushort_t* Wp = (blockIdx.z == 0) ? W0 : (blockIdx.z == 1) ? W1 : W2w;
  void* outp = (blockIdx.z == 0) ? out0 : (blockIdx.z == 1) ? out1 : out2;

  f32x4 acc[2][8];
  #pragma unroll
  for (int s2 = 0; s2 < 2; ++s2)
    #pragma unroll
    for (int nb = 0; nb < 8; ++nb) acc[s2][nb] = (f32x4)0.0f;

  const int row = tid >> 1, half = tid & 1;
  for (int kt = 0; kt < 512; kt += 64) {
    __syncthreads();
    const ushort_t* ag = &A[(size_t)(m0 + row) * 512 + kt + half * 32];
    const ushort_t* bg = &Wp[(size_t)(n0 + row) * 512 + kt + half * 32];
    #pragma unroll
    for (int c = 0; c < 4; ++c)
      *(uint4*)&sA[row][half * 32 + c * 8] = *(const uint4*)&ag[c * 8];
    #pragma unroll
    for (int c = 0; c < 4; ++c)
      *(uint4*)&sB[row][half * 32 + c * 8] = *(const uint4*)&bg[c * 8];
    __syncthreads();
    #pragma unroll
    for (int ks = 0; ks < 2; ++ks) {
      bf16x8 a0 = *(bf16x8*)&sA[w * 32 + l16][ks * 32 + quad * 8];
      bf16x8 a1 = *(bf16x8*)&sA[w * 32 + 16 + l16][ks * 32 + quad * 8];
      #pragma unroll
      for (int nb = 0; nb < 8; ++nb) {
        bf16x8 bfr = *(bf16x8*)&sB[nb * 16 + l16][ks * 32 + quad * 8];
        acc[0][nb] = __builtin_amdgcn_mfma_f32_16x16x32_bf16(a0, bfr, acc[0][nb], 0, 0, 0);
        acc[1][nb] = __builtin_amdgcn_mfma_f32_16x16x32_bf16(a1, bfr, acc[1][nb], 0, 0, 0);
      }
    }
  }
  #pragma unroll
  for (int s2 = 0; s2 < 2; ++s2) {
    #pragma unroll
    for (int nb = 0; nb < 8; ++nb) {
      #pragma unroll
      for (int r = 0; r < 4; ++r) {
        int m = m0 + w * 32 + s2 * 16 + quad * 4 + r;
        int n = n0 + nb * 16 + l16;
        float v = acc[s2][nb][r];
        if (scatter) {
          int bb = m >> 10, ss = m & 1023, hh = n >> 6, kd = n & 63;
          ((ushort_t*)outp)[(((size_t)(bb * NHEAD + hh)) * S_LEN + ss) * KDIM + kd] = f2bf(v);
        } else {
          ((float*)outp)[(size_t)m * 512 + n] = v;
        }
      }
    }
  }
}

// ---------------------------------------------------------------------------
// Kernel 3: MFMA causal flash attention, fragment-order bias, paired Q-tiles.
// Block p handles Q-tiles {15-p, p} (constant 17 K-tile iterations). 4 waves
// x 16 query rows. Q pre-scaled by 1/8 (in Wq). Causal mask baked into bias.
// ---------------------------------------------------------------------------
__global__ __launch_bounds__(256) void fire_attn_mfma(
    const ushort_t* __restrict__ Qg, const ushort_t* __restrict__ Kg,
    const ushort_t* __restrict__ Vg, const ushort_t* __restrict__ biaspre,
    ushort_t* __restrict__ Ob) {
  __shared__ __align__(16) ushort_t Qs[64][72];
  __shared__ __align__(16) ushort_t Ks[64][72];
  __shared__ __align__(16) ushort_t Vt[64][72];   // [kd][j]
  __shared__ __align__(16) ushort_t Ps[64][72];

  const int tid = threadIdx.x;
  const int lane = tid & 63;
  const int w = tid >> 6;
  const int quad = lane >> 4;
  const int l16 = lane & 15;
  const int p = blockIdx.x;              // 0..7
  const int bh = blockIdx.y;
  const int h = bh & (NHEAD - 1);
  const int b = bh >> 3;
  const int i0loc = w * 16 + quad * 4;

  #pragma unroll 1
  for (int pp = 0; pp < 2; ++pp) {
    const int qt = pp ? p : 15 - p;
    __syncthreads();                     // protect Qs from previous round's readers
    {
      const size_t qbase = ((size_t)bh * S_LEN + qt * 64) * KDIM;
      const int qrow = tid >> 2, qseg = tid & 3;
      const ushort_t* qg = &Qg[qbase + qrow * 64 + qseg * 16];
      *(uint4*)&Qs[qrow][qseg * 16] = *(const uint4*)&qg[0];
      *(uint4*)&Qs[qrow][qseg * 16 + 8] = *(const uint4*)&qg[8];
    }

    f32x4 o[4];
    float m[4], l[4];
    #pragma unroll
    for (int nb = 0; nb < 4; ++nb) o[nb] = (f32x4)0.0f;
    #pragma unroll
    for (int r = 0; r < 4; ++r) { m[r] = -INFINITY; l[r] = 0.f; }

    const size_t btile0 = (size_t)h * 136 + TRI(qt);

    for (int t = 0; t <= qt; ++t) {
      const size_t kbase = ((size_t)bh * S_LEN + t * 64) * KDIM;
      __syncthreads();                   // protect Ks/Vt (and publish Qs on t=0)
      {
        const int krow = tid >> 2, kseg = tid & 3;
        const ushort_t* kg = &Kg[kbase + krow * 64 + kseg * 16];
        *(uint4*)&Ks[krow][kseg * 16] = *(const uint4*)&kg[0];
        *(uint4*)&Ks[krow][kseg * 16 + 8] = *(const uint4*)&kg[8];
      }
      {
        const int kd = lane, j0 = w * 16;
        bf16x8 v0, v1;
        #pragma unroll
        for (int jj = 0; jj < 8; ++jj)
          v0[jj] = (short)Vg[kbase + (size_t)(j0 + jj) * 64 + kd];
        #pragma unroll
        for (int jj = 0; jj < 8; ++jj)
          v1[jj] = (short)Vg[kbase + (size_t)(j0 + 8 + jj) * 64 + kd];
        *(bf16x8*)&Vt[kd][j0] = v0;
        *(bf16x8*)&Vt[kd][j0 + 8] = v1;
      }
      __syncthreads();

      // ---- S = (Q/8) K^T
      f32x4 s[4];
      #pragma unroll
      for (int nb = 0; nb < 4; ++nb) s[nb] = (f32x4)0.0f;
      #pragma unroll
      for (int ks = 0; ks < 2; ++ks) {
        bf16x8 aq = *(bf16x8*)&Qs[w * 16 + l16][ks * 32 + quad * 8];
        #pragma unroll
        for (int nb = 0; nb < 4; ++nb) {
          bf16x8 bk = *(bf16x8*)&Ks[nb * 16 + l16][ks * 32 + quad * 8];
          s[nb] = __builtin_amdgcn_mfma_f32_16x16x32_bf16(aq, bk, s[nb], 0, 0, 0);
        }
      }

      // ---- + bias (fragment-order bf16, -inf where masked)
      {
        const uint4* bp = (const uint4*)&biaspre[((btile0 + t) * 256 + tid) * 16];
        uint4 b0 = bp[0], b1 = bp[1];
        #pragma unroll
        for (int nb = 0; nb < 4; ++nb) {
          #pragma unroll
          for (int r = 0; r < 4; ++r) {
            int v = nb * 4 + r;
            ushort_t uu = (v < 8) ? ((ushort_t*)&b0)[v] : ((ushort_t*)&b1)[v - 8];
            s[nb][r] += bf2f(uu);
          }
        }
      }

      // ---- online softmax (row = quad*4+r across 16 lanes)
      float alpha[4];
      #pragma unroll
      for (int r = 0; r < 4; ++r) {
        float rm = fmaxf(fmaxf(s[0][r], s[1][r]), fmaxf(s[2][r], s[3][r]));
        #pragma unroll
        for (int off = 1; off < 16; off <<= 1) rm = fmaxf(rm, __shfl_xor(rm, off));
        float nm = fmaxf(m[r], rm);
        alpha[r] = __expf(m[r] - nm);
        m[r] = nm;
      }
      #pragma unroll
      for (int nb = 0; nb < 4; ++nb)
        #pragma unroll
        for (int r = 0; r < 4; ++r)
          s[nb][r] = __expf(s[nb][r] - m[r]);
      #pragma unroll
      for (int r = 0; r < 4; ++r) {
        float rs = s[0][r] + s[1][r] + s[2][r] + s[3][r];
        #pragma unroll
        for (int off = 1; off < 16; off <<= 1) rs += __shfl_xor(rs, off);
        l[r] = l[r] * alpha[r] + rs;
      }

      // ---- P -> LDS (C-layout -> A-layout), PV
      #pragma unroll
      for (int nb = 0; nb < 4; ++nb)
        #pragma unroll
        for (int r = 0; r < 4; ++r)
          Ps[i0loc + r][nb * 16 + l16] = f2bf(s[nb][r]);

      #pragma unroll
      for (int nb = 0; nb < 4; ++nb) {
        f32x4 ov = o[nb];
        #pragma unroll
        for (int r = 0; r < 4; ++r) ov[r] *= alpha[r];
        o[nb] = ov;
      }
      #pragma unroll
      for (int ks = 0; ks < 2; ++ks) {
        bf16x8 ap = *(bf16x8*)&Ps[w * 16 + l16][ks * 32 + quad * 8];
        #pragma unroll
        for (int nb = 0; nb < 4; ++nb) {
          bf16x8 bv = *(bf16x8*)&Vt[nb * 16 + l16][ks * 32 + quad * 8];
          o[nb] = __builtin_amdgcn_mfma_f32_16x16x32_bf16(ap, bv, o[nb], 0, 0, 0);
        }
      }
    }

    // ---- epilogue: Ob (bf16) [b][i][h*64+col]
    const int i0 = qt * 64 + i0loc;
    #pragma unroll
    for (int r = 0; r < 4; ++r) {
      float rl = 1.0f / l[r];
      size_t ob = ((size_t)(b * S_LEN + i0 + r)) * 512 + h * KDIM;
      #pragma unroll
      for (int nb = 0; nb < 4; ++nb)
        Ob[ob + nb * 16 + l16] = f2bf(o[nb][r] * rl);
    }
  }
}

// ---------------------------------------------------------------------------
extern "C" void kernel_launch(void* const* d_in, const int* in_sizes, int n_in,
                              void* d_out, int out_size, void* d_ws, size_t ws_size,
                              hipStream_t stream) {
  const float* src   = (const float*)d_in[0];
  const float* Wq    = (const float*)d_in[1];
  const float* Wk    = (const float*)d_in[2];
  const float* Wv    = (const float*)d_in[3];
  const float* c_raw = (const float*)d_in[4];
  const float* Lp    = (const float*)d_in[5];
  const float* w1    = (const float*)d_in[6];
  const float* b1    = (const float*)d_in[7];
  const float* W2    = (const float*)d_in[8];
  const float* b2    = (const float*)d_in[9];
  const float* w3    = (const float*)d_in[10];
  const float* b3    = (const float*)d_in[11];
  const float* Wo    = (const float*)d_in[12];
  float* outp = (float*)d_out;

  const size_t SRC_E = 4194304;   // 8*1024*512
  const size_t W_E   = 262144;    // 512*512
  const size_t QKV_E = 4194304;   // 64*1024*64
  ushort_t* srcb = (ushort_t*)d_ws;
  ushort_t* Wqb  = srcb + SRC_E;
  ushort_t* Wkb  = Wqb + W_E;
  ushort_t* Wvb  = Wkb + W_E;
  ushort_t* Wob  = Wvb + W_E;
  ushort_t* Qb   = Wob + W_E;
  ushort_t* Kb   = Qb + QKV_E;
  ushort_t* Vb   = Kb + QKV_E;
  ushort_t* Obb  = Vb + QKV_E;
  ushort_t* biaspre = Obb + QKV_E;                 // 8*136*256*16 = 4,456,448
  float* numb  = (float*)(biaspre + (size_t)NHEAD * 136 * 256 * 16);
  float* rdenb = numb + NHEAD * S_LEN;
  float* gtabb = rdenb + NHEAD * S_LEN;

  hipLaunchKernelGGL(to_bf16, dim3(4096, 5), dim3(256), 0, stream,
                     src, Wq, Wk, Wv, Wo, srcb, Wqb, Wkb, Wvb, Wob);
  hipLaunchKernelGGL(fire_tables, dim3(NHEAD, 8), dim3(256), 0, stream,
                     c_raw, Lp, w1, b1, W2, b2, w3, b3, numb, rdenb, gtabb);
  hipLaunchKernelGGL(fire_bias_pre, dim3(136, NHEAD), dim3(256), 0, stream,
                     numb, rdenb, gtabb, biaspre);
  hipLaunchKernelGGL(gemm_bf16, dim3(64, 4, 3), dim3(256), 0, stream,
                     srcb, Wqb, Wkb, Wvb, (void*)Qb, (void*)Kb, (void*)Vb, 1);
  hipLaunchKernelGGL(fire_attn_mfma, dim3(8, 64), dim3(256), 0, stream,
                     Qb, Kb, Vb, biaspre, Obb);
  hipLaunchKernelGGL(gemm_bf16, dim3(64, 4, 1), dim3(256), 0, stream,
                     Obb, Wob, Wob, Wob, (void*)outp, (void*)outp, (void*)outp, 0);
}

// Round 4
// 210.867 us; speedup vs baseline: 3.7288x; 1.1185x over previous
//
#include <hip/hip_runtime.h>
#include <math.h>

#define S_LEN 1024
#define NHEAD 8
#define BATCH 8
#define KDIM  64
#define HID   32
#define NT    2048
#define TRI(q) ((q) * ((q) + 1) / 2)

typedef __attribute__((ext_vector_type(8))) short bf16x8;
typedef __attribute__((ext_vector_type(4))) float f32x4;
typedef unsigned short ushort_t;

__device__ inline ushort_t f2bf(float f) {
  union { float f; unsigned u; } v; v.f = f;
  unsigned u = v.u;
  return (ushort_t)((u + 0x7FFFu + ((u >> 16) & 1u)) >> 16);
}
__device__ inline float bf2f(ushort_t u) {
  union { unsigned x; float f; } v; v.x = ((unsigned)u) << 16; return v.f;
}

// async global->LDS 16B: lane's LDS dest = lds_base + lane*16 (wave-uniform base)
__device__ inline void gl_lds16(const ushort_t* g, ushort_t* l) {
  __builtin_amdgcn_global_load_lds(
      (const __attribute__((address_space(1))) unsigned int*)g,
      (__attribute__((address_space(3))) unsigned int*)l, 16, 0, 0);
}

// ---------------------------------------------------------------------------
// Kernel 0: f32 -> bf16 pre-convert (src + 4 weights; Wq scaled by 0.125).
// ---------------------------------------------------------------------------
__global__ __launch_bounds__(256) void to_bf16(
    const float* __restrict__ s, const float* __restrict__ wq,
    const float* __restrict__ wk, const float* __restrict__ wv,
    const float* __restrict__ wo,
    ushort_t* __restrict__ sb, ushort_t* __restrict__ wqb,
    ushort_t* __restrict__ wkb, ushort_t* __restrict__ wvb,
    ushort_t* __restrict__ wob) {
  const int y = blockIdx.y;
  const float* src; ushort_t* dst; int n; float scale = 1.0f;
  if (y == 0)      { src = s;  dst = sb;  n = 4194304; }
  else if (y == 1) { src = wq; dst = wqb; n = 262144; scale = 0.125f; }
  else if (y == 2) { src = wk; dst = wkb; n = 262144; }
  else if (y == 3) { src = wv; dst = wvb; n = 262144; }
  else             { src = wo; dst = wob; n = 262144; }
  const int i = (blockIdx.x * 256 + threadIdx.x) * 4;
  if (i < n) {
    float4 v = *(const float4*)&src[i];
    ushort4 o;
    o.x = f2bf(v.x * scale); o.y = f2bf(v.y * scale);
    o.z = f2bf(v.z * scale); o.w = f2bf(v.w * scale);
    *(ushort4*)&dst[i] = o;
  }
}

// ---------------------------------------------------------------------------
// Kernel 1: FIRE tables.
// ---------------------------------------------------------------------------
__global__ void fire_tables(const float* __restrict__ c_raw, const float* __restrict__ Lp,
                            const float* __restrict__ w1, const float* __restrict__ b1,
                            const float* __restrict__ W2, const float* __restrict__ b2,
                            const float* __restrict__ w3, const float* __restrict__ b3,
                            float* __restrict__ num_g, float* __restrict__ rden_g,
                            float* __restrict__ gtab_g) {
  const int h = blockIdx.x;
  const int tid0 = blockIdx.y * 256 + threadIdx.x;   // 0..2047
  const float cr = c_raw[h];
  const float c = (cr > 20.f) ? cr : log1pf(expf(cr));
  const float Lh = Lp[h];
  for (int i = tid0; i < S_LEN; i += 2048) {
    num_g[h * S_LEN + i] = log1pf(c * (float)i);
    rden_g[h * S_LEN + i] = 1.0f / log1pf(c * fmaxf(Lh, (float)(i + 1)));
  }
  for (int t = tid0; t <= NT; t += 2048) {
    const float x = (float)t * (1.0f / NT);
    float h1[HID];
    #pragma unroll
    for (int j = 0; j < HID; ++j) {
      float v = x * w1[h * HID + j] + b1[h * HID + j];
      h1[j] = 0.5f * v * (1.0f + erff(v * 0.70710678118f));
    }
    float y = b3[h];
    for (int j = 0; j < HID; ++j) {
      float s = b2[h * HID + j];
      const float* w2r = W2 + ((size_t)(h * HID + j)) * HID;
      #pragma unroll
      for (int k = 0; k < HID; ++k) s += w2r[k] * h1[k];
      float g = 0.5f * s * (1.0f + erff(s * 0.70710678118f));
      y += w3[h * HID + j] * g;
    }
    gtab_g[h * (NT + 1) + t] = y;
  }
}

// ---------------------------------------------------------------------------
// Kernel 1b: bias in MFMA fragment order, causal -inf baked in.
// biaspre[h][TRI(qt)+t][tid][16 bf16]; v=nb*4+r -> row i = qt*64+(tid>>6)*16+
// ((tid&63)>>4)*4+r, col j = t*64+nb*16+(tid&15).
// ---------------------------------------------------------------------------
__global__ __launch_bounds__(256) void fire_bias_pre(
    const float* __restrict__ num_g, const float* __restrict__ rden_g,
    const float* __restrict__ gtab_g, ushort_t* __restrict__ biaspre) {
  __shared__ float gtab_s[NT + 1];
  __shared__ float num_s[S_LEN];
  __shared__ float rden_s[64];
  const int tid = threadIdx.x;
  const int h = blockIdx.y;
  const int tileIdx = blockIdx.x;          // 0..135
  int qt = 0;
  while (TRI(qt + 1) <= tileIdx) ++qt;
  const int t = tileIdx - TRI(qt);
  for (int i = tid; i <= NT; i += 256) gtab_s[i] = gtab_g[h * (NT + 1) + i];
  for (int i = tid; i < S_LEN; i += 256) num_s[i] = num_g[h * S_LEN + i];
  if (tid < 64) rden_s[tid] = rden_g[h * S_LEN + qt * 64 + tid];
  __syncthreads();
  const int lane = tid & 63, w = tid >> 6, quad = lane >> 4, l16 = lane & 15;
  ushort_t vals[16];
  #pragma unroll
  for (int nb = 0; nb < 4; ++nb) {
    #pragma unroll
    for (int r = 0; r < 4; ++r) {
      const int iloc = w * 16 + quad * 4 + r;
      const int i = qt * 64 + iloc;
      const int j = t * 64 + nb * 16 + l16;
      ushort_t out;
      if (j > i) {
        out = 0xFF80;  // bf16 -inf
      } else {
        const int d = i - j;
        float x = num_s[d] * rden_s[iloc];
        float tf = x * (float)NT;
        int it = (int)tf; it = it < (NT - 1) ? it : (NT - 1);
        float fr = tf - (float)it;
        float ga = gtab_s[it];
        out = f2bf(ga + (gtab_s[it + 1] - ga) * fr);
      }
      vals[nb * 4 + r] = out;
    }
  }
  ushort_t* dst = &biaspre[(((size_t)h * 136 + tileIdx) * 256 + tid) * 16];
  uint4 lo, hi;
  #pragma unroll
  for (int v = 0; v < 8; ++v) { ((ushort_t*)&lo)[v] = vals[v]; ((ushort_t*)&hi)[v] = vals[v + 8]; }
  *(uint4*)dst = lo;
  *(uint4*)(dst + 8) = hi;
}

// ---------------------------------------------------------------------------
// Kernel 2: bf16 MFMA GEMM, C = A(Mx512) * W^T (512x512, NxK). 128x128 tile,
// BK=64, global_load_lds staging into XOR-swizzled unpadded LDS.
// scatter=1: z<2 -> bf16 [b,h,s,kd]; z==2 -> V^T bf16 [b,h,kd,s] (LDS transpose).
// scatter=0: f32 row-major Mx512.
// ---------------------------------------------------------------------------
__global__ __launch_bounds__(256) void gemm_bf16(
    const ushort_t* __restrict__ A,
    const ushort_t* __restrict__ W0, const ushort_t* __restrict__ W1,
    const ushort_t* __restrict__ W2w,
    void* __restrict__ out0, void* __restrict__ out1, void* __restrict__ out2,
    int scatter) {
  __shared__ __align__(16) ushort_t sAB[16384];   // sA [0,8192), sB [8192,16384)
  ushort_t* sA = sAB;
  ushort_t* sB = sAB + 8192;
  const int tid = threadIdx.x;
  const int lane = tid & 63;
  const int w = tid >> 6;
  const int quad = lane >> 4;
  const int l16 = lane & 15;
  const int m0 = blockIdx.x * 128;
  const int n0 = blockIdx.y * 128;
  const int z = blockIdx.z;
  const ushort_t* Wp = (z == 0) ? W0 : (z == 1) ? W1 : W2w;
  void* outp = (z == 0) ? out0 : (z == 1) ? out1 : out2;
  const int mode = scatter ? ((z == 2) ? 2 : 1) : 0;

  f32x4 acc[2][8];
  #pragma unroll
  for (int s2 = 0; s2 < 2; ++s2)
    #pragma unroll
    for (int nb = 0; nb < 8; ++nb) acc[s2][nb] = (f32x4)0.0f;

  const int r8 = lane >> 3;          // row within 8-row group
  const int gc = (lane & 7) ^ r8;    // swizzled global chunk for this lane
  const int sw = l16 & 7;            // frag-read swizzle

  for (int kt = 0; kt < 512; kt += 64) {
    __syncthreads();
    #pragma unroll
    for (int j = 0; j < 4; ++j) {
      const int row = j * 32 + w * 8 + r8;
      gl_lds16(&A[(size_t)(m0 + row) * 512 + kt + gc * 8], &sA[(j * 32 + w * 8) * 64]);
      gl_lds16(&Wp[(size_t)(n0 + row) * 512 + kt + gc * 8], &sB[(j * 32 + w * 8) * 64]);
    }
    __syncthreads();
    #pragma unroll
    for (int ks = 0; ks < 2; ++ks) {
      const int c = ks * 4 + quad;
      const int off = ((c ^ sw) * 8);
      bf16x8 a0 = *(bf16x8*)&sA[(w * 32 + l16) * 64 + off];
      bf16x8 a1 = *(bf16x8*)&sA[(w * 32 + 16 + l16) * 64 + off];
      #pragma unroll
      for (int nb = 0; nb < 8; ++nb) {
        bf16x8 bfr = *(bf16x8*)&sB[(nb * 16 + l16) * 64 + off];
        acc[0][nb] = __builtin_amdgcn_mfma_f32_16x16x32_bf16(a0, bfr, acc[0][nb], 0, 0, 0);
        acc[1][nb] = __builtin_amdgcn_mfma_f32_16x16x32_bf16(a1, bfr, acc[1][nb], 0, 0, 0);
      }
    }
  }

  if (mode == 2) {
    // V^T: acc -> LDS (XOR-swizzled [n][m]) -> coalesced [b,h,kd,s] stores
    __syncthreads();
    #pragma unroll
    for (int s2 = 0; s2 < 2; ++s2)
      #pragma unroll
      for (int nb = 0; nb < 8; ++nb)
        #pragma unroll
        for (int r = 0; r < 4; ++r) {
          int nl = nb * 16 + l16;
          int ml = w * 32 + s2 * 16 + quad * 4 + r;
          sAB[nl * 128 + (((ml >> 3) ^ (nl & 7)) * 8) + (ml & 7)] = f2bf(acc[s2][nb][r]);
        }
    __syncthreads();
    const int nl = tid >> 1, halfm = tid & 1;
    const int ng = n0 + nl, hh = ng >> 6, kd = ng & 63;
    const int bb = m0 >> 10, sbase = m0 & 1023;
    ushort_t* vout = (ushort_t*)outp + (((size_t)(bb * NHEAD + hh)) * KDIM + kd) * S_LEN;
    #pragma unroll
    for (int c2 = 0; c2 < 8; ++c2) {
      int mc = halfm * 8 + c2;
      bf16x8 vr = *(bf16x8*)&sAB[nl * 128 + ((mc ^ (nl & 7)) * 8)];
      *(bf16x8*)&vout[sbase + mc * 8] = vr;
    }
    return;
  }
  #pragma unroll
  for (int s2 = 0; s2 < 2; ++s2) {
    #pragma unroll
    for (int nb = 0; nb < 8; ++nb) {
      #pragma unroll
      for (int r = 0; r < 4; ++r) {
        int m = m0 + w * 32 + s2 * 16 + quad * 4 + r;
        int n = n0 + nb * 16 + l16;
        float v = acc[s2][nb][r];
        if (mode == 1) {
          int bb = m >> 10, ss = m & 1023, hh = n >> 6, kd = n & 63;
          ((ushort_t*)outp)[(((size_t)(bb * NHEAD + hh)) * S_LEN + ss) * KDIM + kd] = f2bf(v);
        } else {
          ((float*)outp)[(size_t)m * 512 + n] = v;
        }
      }
    }
  }
}

// ---------------------------------------------------------------------------
// Kernel 3: MFMA causal flash attention. One block per (qt, b, h); 4 waves x
// 16 Q-rows. No-max softmax (exp safe: |logit| <~ 8), l accumulated per-lane,
// reduced once at epilogue. K/V^T prefetched into regs one tile ahead.
// qt map g<8?15-g:g-8 balances iterations across CUs (34 per CU slot).
// ---------------------------------------------------------------------------
__global__ __launch_bounds__(256) void fire_attn_mfma(
    const ushort_t* __restrict__ Qg, const ushort_t* __restrict__ Kg,
    const ushort_t* __restrict__ Vtg, const ushort_t* __restrict__ biaspre,
    ushort_t* __restrict__ Ob) {
  __shared__ __align__(16) ushort_t Ks[64][72];
  __shared__ __align__(16) ushort_t Vt[64][72];
  __shared__ __align__(16) ushort_t Ps[64][72];

  const int tid = threadIdx.x;
  const int lane = tid & 63;
  const int w = tid >> 6;
  const int quad = lane >> 4;
  const int l16 = lane & 15;
  const int g = blockIdx.x >> 6;
  const int qt = (g < 8) ? (15 - g) : (g - 8);
  const int bh = blockIdx.x & 63;
  const int h = bh & (NHEAD - 1);
  const int b = bh >> 3;

  // Q fragments straight from global (A-layout: row=l16-strip, k=quad*8)
  const size_t qrow = (size_t)bh * S_LEN + qt * 64 + w * 16 + l16;
  bf16x8 aq0 = *(const bf16x8*)&Qg[qrow * KDIM + quad * 8];
  bf16x8 aq1 = *(const bf16x8*)&Qg[qrow * KDIM + 32 + quad * 8];

  // staging map: krow = tid>>2 (0..63), kseg = tid&3 (16 ushorts each)
  const int krow = tid >> 2, kseg = tid & 3;
  const size_t kb = (size_t)bh * S_LEN * KDIM;
  const ushort_t* kptr = &Kg[kb + (size_t)krow * 64 + kseg * 16];    // + t*4096
  const ushort_t* vptr = &Vtg[kb + (size_t)krow * 1024 + kseg * 16]; // + t*64
  const ushort_t* bptr = &biaspre[(((size_t)h * 136 + TRI(qt)) * 256 + tid) * 16];

  uint4 kr0 = *(const uint4*)(kptr);
  uint4 kr1 = *(const uint4*)(kptr + 8);
  uint4 vr0 = *(const uint4*)(vptr);
  uint4 vr1 = *(const uint4*)(vptr + 8);

  f32x4 o[4];
  float ll[4];
  #pragma unroll
  for (int nb = 0; nb < 4; ++nb) o[nb] = (f32x4)0.0f;
  #pragma unroll
  for (int r = 0; r < 4; ++r) ll[r] = 0.f;
  const int i0loc = w * 16 + quad * 4;

  for (int t = 0; t <= qt; ++t) {
    __syncthreads();                       // Ks/Vt/Ps consumed
    *(uint4*)&Ks[krow][kseg * 16] = kr0;
    *(uint4*)&Ks[krow][kseg * 16 + 8] = kr1;
    *(uint4*)&Vt[krow][kseg * 16] = vr0;
    *(uint4*)&Vt[krow][kseg * 16 + 8] = vr1;
    __syncthreads();

    // bias for current tile (outstanding during QK), then prefetch t+1 K/V
    uint4 bb0 = *(const uint4*)(bptr + (size_t)t * 4096);
    uint4 bb1 = *(const uint4*)(bptr + (size_t)t * 4096 + 8);
    if (t < qt) {
      kr0 = *(const uint4*)(kptr + (size_t)(t + 1) * 4096);
      kr1 = *(const uint4*)(kptr + (size_t)(t + 1) * 4096 + 8);
      vr0 = *(const uint4*)(vptr + (size_t)(t + 1) * 64);
      vr1 = *(const uint4*)(vptr + (size_t)(t + 1) * 64 + 8);
    }

    // ---- S = (Q/8) K^T
    f32x4 s[4];
    #pragma unroll
    for (int nb = 0; nb < 4; ++nb) s[nb] = (f32x4)0.0f;
    #pragma unroll
    for (int ks = 0; ks < 2; ++ks) {
      bf16x8 aq = ks ? aq1 : aq0;
      #pragma unroll
      for (int nb = 0; nb < 4; ++nb) {
        bf16x8 bk = *(bf16x8*)&Ks[nb * 16 + l16][ks * 32 + quad * 8];
        s[nb] = __builtin_amdgcn_mfma_f32_16x16x32_bf16(aq, bk, s[nb], 0, 0, 0);
      }
    }

    // ---- p = exp(s + bias)  (bias holds -inf for masked) ; accumulate l
    #pragma unroll
    for (int nb = 0; nb < 4; ++nb) {
      #pragma unroll
      for (int r = 0; r < 4; ++r) {
        int v = nb * 4 + r;
        ushort_t bu = (v < 8) ? ((ushort_t*)&bb0)[v] : ((ushort_t*)&bb1)[v - 8];
        float p = __expf(s[nb][r] + bf2f(bu));
        ushort_t pu = f2bf(p);
        Ps[i0loc + r][nb * 16 + l16] = pu;
        ll[r] += bf2f(pu);                  // consistent with bf16 P used in PV
      }
    }

    // ---- O += P V  (wave-private Ps strip; same-wave write->read, no barrier)
    #pragma unroll
    for (int ks = 0; ks < 2; ++ks) {
      bf16x8 ap = *(bf16x8*)&Ps[w * 16 + l16][ks * 32 + quad * 8];
      #pragma unroll
      for (int nb = 0; nb < 4; ++nb) {
        bf16x8 bv = *(bf16x8*)&Vt[nb * 16 + l16][ks * 32 + quad * 8];
        o[nb] = __builtin_amdgcn_mfma_f32_16x16x32_bf16(ap, bv, o[nb], 0, 0, 0);
      }
    }
  }

  // ---- epilogue: reduce l across the 16 lanes once, store O/l (bf16)
  const int i0 = qt * 64 + i0loc;
  #pragma unroll
  for (int r = 0; r < 4; ++r) {
    float rs = ll[r];
    #pragma unroll
    for (int off = 1; off < 16; off <<= 1) rs += __shfl_xor(rs, off);
    float rl = 1.0f / rs;
    size_t ob = ((size_t)(b * S_LEN + i0 + r)) * 512 + h * KDIM;
    #pragma unroll
    for (int nb = 0; nb < 4; ++nb)
      Ob[ob + nb * 16 + l16] = f2bf(o[nb][r] * rl);
  }
}

// ---------------------------------------------------------------------------
extern "C" void kernel_launch(void* const* d_in, const int* in_sizes, int n_in,
                              void* d_out, int out_size, void* d_ws, size_t ws_size,
                              hipStream_t stream) {
  const float* src   = (const float*)d_in[0];
  const float* Wq    = (const float*)d_in[1];
  const float* Wk    = (const float*)d_in[2];
  const float* Wv    = (const float*)d_in[3];
  const float* c_raw = (const float*)d_in[4];
  const float* Lp    = (const float*)d_in[5];
  const float* w1    = (const float*)d_in[6];
  const float* b1    = (const float*)d_in[7];
  const float* W2    = (const float*)d_in[8];
  const float* b2    = (const float*)d_in[9];
  const float* w3    = (const float*)d_in[10];
  const float* b3    = (const float*)d_in[11];
  const float* Wo    = (const float*)d_in[12];
  float* outp = (float*)d_out;

  const size_t SRC_E = 4194304;   // 8*1024*512
  const size_t W_E   = 262144;    // 512*512
  const size_t QKV_E = 4194304;   // 64*1024*64
  ushort_t* srcb = (ushort_t*)d_ws;
  ushort_t* Wqb  = srcb + SRC_E;
  ushort_t* Wkb  = Wqb + W_E;
  ushort_t* Wvb  = Wkb + W_E;
  ushort_t* Wob  = Wvb + W_E;
  ushort_t* Qb   = Wob + W_E;
  ushort_t* Kb   = Qb + QKV_E;
  ushort_t* Vtb  = Kb + QKV_E;    // V transposed: [b,h,kd,s]
  ushort_t* Obb  = Vtb + QKV_E;
  ushort_t* biaspre = Obb + QKV_E;                 // 8*136*256*16
  float* numb  = (float*)(biaspre + (size_t)NHEAD * 136 * 256 * 16);
  float* rdenb = numb + NHEAD * S_LEN;
  float* gtabb = rdenb + NHEAD * S_LEN;

  hipLaunchKernelGGL(to_bf16, dim3(4096, 5), dim3(256), 0, stream,
                     src, Wq, Wk, Wv, Wo, srcb, Wqb, Wkb, Wvb, Wob);
  hipLaunchKernelGGL(fire_tables, dim3(NHEAD, 8), dim3(256), 0, stream,
                     c_raw, Lp, w1, b1, W2, b2, w3, b3, numb, rdenb, gtabb);
  hipLaunchKernelGGL(fire_bias_pre, dim3(136, NHEAD), dim3(256), 0, stream,
                     numb, rdenb, gtabb, biaspre);
  hipLaunchKernelGGL(gemm_bf16, dim3(64, 4, 3), dim3(256), 0, stream,
                     srcb, Wqb, Wkb, Wvb, (void*)Qb, (void*)Kb, (void*)Vtb, 1);
  hipLaunchKernelGGL(fire_attn_mfma, dim3(1024), dim3(256), 0, stream,
                     Qb, Kb, Vtb, biaspre, Obb);
  hipLaunchKernelGGL(gemm_bf16, dim3(64, 4, 1), dim3(256), 0, stream,
                     Obb, Wob, Wob, Wob, (void*)outp, (void*)outp, (void*)outp, 0);
}

// Round 5
// 181.752 us; speedup vs baseline: 4.3262x; 1.1602x over previous
//
#include <hip/hip_runtime.h>
#include <math.h>

#define S_LEN 1024
#define NHEAD 8
#define BATCH 8
#define KDIM  64
#define HID   32
#define NT    2048
#define TRI(q) ((q) * ((q) + 1) / 2)

typedef __attribute__((ext_vector_type(8))) short bf16x8;
typedef __attribute__((ext_vector_type(4))) float f32x4;
typedef unsigned short ushort_t;

__device__ inline ushort_t f2bf(float f) {
  union { float f; unsigned u; } v; v.f = f;
  unsigned u = v.u;
  return (ushort_t)((u + 0x7FFFu + ((u >> 16) & 1u)) >> 16);
}
__device__ inline float bf2f(ushort_t u) {
  union { unsigned x; float f; } v; v.x = ((unsigned)u) << 16; return v.f;
}

// async global->LDS 16B: lane's LDS dest = lds_base + lane*16 (wave-uniform base)
__device__ inline void gl_lds16(const ushort_t* g, ushort_t* l) {
  __builtin_amdgcn_global_load_lds(
      (const __attribute__((address_space(1))) unsigned int*)g,
      (__attribute__((address_space(3))) unsigned int*)l, 16, 0, 0);
}

// ---------------------------------------------------------------------------
// Kernel 0: f32 -> bf16 pre-convert (src + 4 weights; Wq scaled by 0.125).
// ---------------------------------------------------------------------------
__global__ __launch_bounds__(256) void to_bf16(
    const float* __restrict__ s, const float* __restrict__ wq,
    const float* __restrict__ wk, const float* __restrict__ wv,
    const float* __restrict__ wo,
    ushort_t* __restrict__ sb, ushort_t* __restrict__ wqb,
    ushort_t* __restrict__ wkb, ushort_t* __restrict__ wvb,
    ushort_t* __restrict__ wob) {
  const int y = blockIdx.y;
  const float* src; ushort_t* dst; int n; float scale = 1.0f;
  if (y == 0)      { src = s;  dst = sb;  n = 4194304; }
  else if (y == 1) { src = wq; dst = wqb; n = 262144; scale = 0.125f; }
  else if (y == 2) { src = wk; dst = wkb; n = 262144; }
  else if (y == 3) { src = wv; dst = wvb; n = 262144; }
  else             { src = wo; dst = wob; n = 262144; }
  const int i = (blockIdx.x * 256 + threadIdx.x) * 4;
  if (i < n) {
    float4 v = *(const float4*)&src[i];
    ushort4 o;
    o.x = f2bf(v.x * scale); o.y = f2bf(v.y * scale);
    o.z = f2bf(v.z * scale); o.w = f2bf(v.w * scale);
    *(ushort4*)&dst[i] = o;
  }
}

// ---------------------------------------------------------------------------
// Kernel 1: FIRE tables, wave-parallel MLP. 32 lanes cooperate per table
// point (lane j = hidden dim j): serial erf chain 64 -> 2, full-grid occupancy.
// Grid (257, NHEAD); block covers 8 points. First 4 blocks/head also fill
// num[h][d]=log1p(c*d), rden[h][i]=1/log1p(c*max(L,i+1)).
// ---------------------------------------------------------------------------
__global__ __launch_bounds__(256) void fire_tables(
    const float* __restrict__ c_raw, const float* __restrict__ Lp,
    const float* __restrict__ w1, const float* __restrict__ b1,
    const float* __restrict__ W2, const float* __restrict__ b2,
    const float* __restrict__ w3, const float* __restrict__ b3,
    float* __restrict__ num_g, float* __restrict__ rden_g,
    float* __restrict__ gtab_g) {
  __shared__ float h1s[8][33];
  const int h = blockIdx.y;
  const int tid = threadIdx.x;
  const int pl = tid >> 5;                 // point-local 0..7
  const int j = tid & 31;                  // hidden dim
  const int pt = blockIdx.x * 8 + pl;      // table point 0..2055
  const float cr = c_raw[h];
  const float c = (cr > 20.f) ? cr : log1pf(expf(cr));
  const int gid = blockIdx.x * 256 + tid;
  if (gid < S_LEN) {
    num_g[h * S_LEN + gid] = log1pf(c * (float)gid);
    rden_g[h * S_LEN + gid] = 1.0f / log1pf(c * fmaxf(Lp[h], (float)(gid + 1)));
  }
  const float x = (float)pt * (1.0f / NT);
  float v = x * w1[h * HID + j] + b1[h * HID + j];
  h1s[pl][j] = 0.5f * v * (1.0f + erff(v * 0.70710678118f));
  __syncthreads();
  float s = b2[h * HID + j];
  const float* w2r = W2 + ((size_t)(h * HID + j)) * HID;
  #pragma unroll
  for (int k = 0; k < HID; ++k) s += w2r[k] * h1s[pl][k];
  float g = 0.5f * s * (1.0f + erff(s * 0.70710678118f));
  float y = w3[h * HID + j] * g;
  #pragma unroll
  for (int off = 1; off < 32; off <<= 1) y += __shfl_xor(y, off);  // stays in 32-group
  if (j == 0 && pt <= NT) gtab_g[h * (NT + 1) + pt] = y + b3[h];
}

// ---------------------------------------------------------------------------
// Kernel 1b: bias in MFMA fragment order, causal -inf baked in.
// biaspre[h][TRI(qt)+t][tid][16 bf16]; v=nb*4+r -> row i = qt*64+(tid>>6)*16+
// ((tid&63)>>4)*4+r, col j = t*64+nb*16+(tid&15).
// ---------------------------------------------------------------------------
__global__ __launch_bounds__(256) void fire_bias_pre(
    const float* __restrict__ num_g, const float* __restrict__ rden_g,
    const float* __restrict__ gtab_g, ushort_t* __restrict__ biaspre) {
  __shared__ float gtab_s[NT + 1];
  __shared__ float num_s[S_LEN];
  __shared__ float rden_s[64];
  const int tid = threadIdx.x;
  const int h = blockIdx.y;
  const int tileIdx = blockIdx.x;          // 0..135
  int qt = 0;
  while (TRI(qt + 1) <= tileIdx) ++qt;
  const int t = tileIdx - TRI(qt);
  for (int i = tid; i <= NT; i += 256) gtab_s[i] = gtab_g[h * (NT + 1) + i];
  for (int i = tid; i < S_LEN; i += 256) num_s[i] = num_g[h * S_LEN + i];
  if (tid < 64) rden_s[tid] = rden_g[h * S_LEN + qt * 64 + tid];
  __syncthreads();
  const int lane = tid & 63, w = tid >> 6, quad = lane >> 4, l16 = lane & 15;
  ushort_t vals[16];
  #pragma unroll
  for (int nb = 0; nb < 4; ++nb) {
    #pragma unroll
    for (int r = 0; r < 4; ++r) {
      const int iloc = w * 16 + quad * 4 + r;
      const int i = qt * 64 + iloc;
      const int j = t * 64 + nb * 16 + l16;
      ushort_t out;
      if (j > i) {
        out = 0xFF80;  // bf16 -inf
      } else {
        const int d = i - j;
        float x = num_s[d] * rden_s[iloc];
        float tf = x * (float)NT;
        int it = (int)tf; it = it < (NT - 1) ? it : (NT - 1);
        float fr = tf - (float)it;
        float ga = gtab_s[it];
        out = f2bf(ga + (gtab_s[it + 1] - ga) * fr);
      }
      vals[nb * 4 + r] = out;
    }
  }
  ushort_t* dst = &biaspre[(((size_t)h * 136 + tileIdx) * 256 + tid) * 16];
  uint4 lo, hi;
  #pragma unroll
  for (int v = 0; v < 8; ++v) { ((ushort_t*)&lo)[v] = vals[v]; ((ushort_t*)&hi)[v] = vals[v + 8]; }
  *(uint4*)dst = lo;
  *(uint4*)(dst + 8) = hi;
}

// ---------------------------------------------------------------------------
// Kernel 2: bf16 MFMA GEMM, C = A(Mx512) * W^T (512x512, NxK). 128x128 tile,
// BK=64, global_load_lds staging into XOR-swizzled unpadded LDS.
// scatter=1: z<2 -> bf16 [b,h,s,kd]; z==2 -> V^T bf16 [b,h,kd,s] (LDS transpose).
// scatter=0: f32 row-major Mx512.
// ---------------------------------------------------------------------------
__global__ __launch_bounds__(256) void gemm_bf16(
    const ushort_t* __restrict__ A,
    const ushort_t* __restrict__ W0, const ushort_t* __restrict__ W1,
    const ushort_t* __restrict__ W2w,
    void* __restrict__ out0, void* __restrict__ out1, void* __restrict__ out2,
    int scatter) {
  __shared__ __align__(16) ushort_t sAB[16384];   // sA [0,8192), sB [8192,16384)
  ushort_t* sA = sAB;
  ushort_t* sB = sAB + 8192;
  const int tid = threadIdx.x;
  const int lane = tid & 63;
  const int w = tid >> 6;
  const int quad = lane >> 4;
  const int l16 = lane & 15;
  const int m0 = blockIdx.x * 128;
  const int n0 = blockIdx.y * 128;
  const int z = blockIdx.z;
  const ushort_t* Wp = (z == 0) ? W0 : (z == 1) ? W1 : W2w;
  void* outp = (z == 0) ? out0 : (z == 1) ? out1 : out2;
  const int mode = scatter ? ((z == 2) ? 2 : 1) : 0;

  f32x4 acc[2][8];
  #pragma unroll
  for (int s2 = 0; s2 < 2; ++s2)
    #pragma unroll
    for (int nb = 0; nb < 8; ++nb) acc[s2][nb] = (f32x4)0.0f;

  const int r8 = lane >> 3;          // row within 8-row group
  const int gc = (lane & 7) ^ r8;    // swizzled global chunk for this lane
  const int sw = l16 & 7;            // frag-read swizzle

  for (int kt = 0; kt < 512; kt += 64) {
    __syncthreads();
    #pragma unroll
    for (int j = 0; j < 4; ++j) {
      const int row = j * 32 + w * 8 + r8;
      gl_lds16(&A[(size_t)(m0 + row) * 512 + kt + gc * 8], &sA[(j * 32 + w * 8) * 64]);
      gl_lds16(&Wp[(size_t)(n0 + row) * 512 + kt + gc * 8], &sB[(j * 32 + w * 8) * 64]);
    }
    __syncthreads();
    #pragma unroll
    for (int ks = 0; ks < 2; ++ks) {
      const int c = ks * 4 + quad;
      const int off = ((c ^ sw) * 8);
      bf16x8 a0 = *(bf16x8*)&sA[(w * 32 + l16) * 64 + off];
      bf16x8 a1 = *(bf16x8*)&sA[(w * 32 + 16 + l16) * 64 + off];
      #pragma unroll
      for (int nb = 0; nb < 8; ++nb) {
        bf16x8 bfr = *(bf16x8*)&sB[(nb * 16 + l16) * 64 + off];
        acc[0][nb] = __builtin_amdgcn_mfma_f32_16x16x32_bf16(a0, bfr, acc[0][nb], 0, 0, 0);
        acc[1][nb] = __builtin_amdgcn_mfma_f32_16x16x32_bf16(a1, bfr, acc[1][nb], 0, 0, 0);
      }
    }
  }

  if (mode == 2) {
    // V^T: acc -> LDS (XOR-swizzled [n][m]) -> coalesced [b,h,kd,s] stores
    __syncthreads();
    #pragma unroll
    for (int s2 = 0; s2 < 2; ++s2)
      #pragma unroll
      for (int nb = 0; nb < 8; ++nb)
        #pragma unroll
        for (int r = 0; r < 4; ++r) {
          int nl = nb * 16 + l16;
          int ml = w * 32 + s2 * 16 + quad * 4 + r;
          sAB[nl * 128 + (((ml >> 3) ^ (nl & 7)) * 8) + (ml & 7)] = f2bf(acc[s2][nb][r]);
        }
    __syncthreads();
    const int nl = tid >> 1, halfm = tid & 1;
    const int ng = n0 + nl, hh = ng >> 6, kd = ng & 63;
    const int bb = m0 >> 10, sbase = m0 & 1023;
    ushort_t* vout = (ushort_t*)outp + (((size_t)(bb * NHEAD + hh)) * KDIM + kd) * S_LEN;
    #pragma unroll
    for (int c2 = 0; c2 < 8; ++c2) {
      int mc = halfm * 8 + c2;
      bf16x8 vr = *(bf16x8*)&sAB[nl * 128 + ((mc ^ (nl & 7)) * 8)];
      *(bf16x8*)&vout[sbase + mc * 8] = vr;
    }
    return;
  }
  #pragma unroll
  for (int s2 = 0; s2 < 2; ++s2) {
    #pragma unroll
    for (int nb = 0; nb < 8; ++nb) {
      #pragma unroll
      for (int r = 0; r < 4; ++r) {
        int m = m0 + w * 32 + s2 * 16 + quad * 4 + r;
        int n = n0 + nb * 16 + l16;
        float v = acc[s2][nb][r];
        if (mode == 1) {
          int bb = m >> 10, ss = m & 1023, hh = n >> 6, kd = n & 63;
          ((ushort_t*)outp)[(((size_t)(bb * NHEAD + hh)) * S_LEN + ss) * KDIM + kd] = f2bf(v);
        } else {
          ((float*)outp)[(size_t)m * 512 + n] = v;
        }
      }
    }
  }
}

// ---------------------------------------------------------------------------
// Kernel 3: MFMA causal flash attention. One block per (qt, b, h); 4 waves x
// 16 Q-rows. No-max softmax (exp safe: |logit| <~ 8), l accumulated per-lane,
// reduced once at epilogue. K/V^T prefetched into regs one tile ahead.
// qt map g<8?15-g:g-8 balances iterations across CUs (34 per CU slot).
// ---------------------------------------------------------------------------
__global__ __launch_bounds__(256) void fire_attn_mfma(
    const ushort_t* __restrict__ Qg, const ushort_t* __restrict__ Kg,
    const ushort_t* __restrict__ Vtg, const ushort_t* __restrict__ biaspre,
    ushort_t* __restrict__ Ob) {
  __shared__ __align__(16) ushort_t Ks[64][72];
  __shared__ __align__(16) ushort_t Vt[64][72];
  __shared__ __align__(16) ushort_t Ps[64][72];

  const int tid = threadIdx.x;
  const int lane = tid & 63;
  const int w = tid >> 6;
  const int quad = lane >> 4;
  const int l16 = lane & 15;
  const int g = blockIdx.x >> 6;
  const int qt = (g < 8) ? (15 - g) : (g - 8);
  const int bh = blockIdx.x & 63;
  const int h = bh & (NHEAD - 1);
  const int b = bh >> 3;

  // Q fragments straight from global (A-layout: row=l16-strip, k=quad*8)
  const size_t qrow = (size_t)bh * S_LEN + qt * 64 + w * 16 + l16;
  bf16x8 aq0 = *(const bf16x8*)&Qg[qrow * KDIM + quad * 8];
  bf16x8 aq1 = *(const bf16x8*)&Qg[qrow * KDIM + 32 + quad * 8];

  // staging map: krow = tid>>2 (0..63), kseg = tid&3 (16 ushorts each)
  const int krow = tid >> 2, kseg = tid & 3;
  const size_t kb = (size_t)bh * S_LEN * KDIM;
  const ushort_t* kptr = &Kg[kb + (size_t)krow * 64 + kseg * 16];    // + t*4096
  const ushort_t* vptr = &Vtg[kb + (size_t)krow * 1024 + kseg * 16]; // + t*64
  const ushort_t* bptr = &biaspre[(((size_t)h * 136 + TRI(qt)) * 256 + tid) * 16];

  uint4 kr0 = *(const uint4*)(kptr);
  uint4 kr1 = *(const uint4*)(kptr + 8);
  uint4 vr0 = *(const uint4*)(vptr);
  uint4 vr1 = *(const uint4*)(vptr + 8);

  f32x4 o[4];
  float ll[4];
  #pragma unroll
  for (int nb = 0; nb < 4; ++nb) o[nb] = (f32x4)0.0f;
  #pragma unroll
  for (int r = 0; r < 4; ++r) ll[r] = 0.f;
  const int i0loc = w * 16 + quad * 4;

  for (int t = 0; t <= qt; ++t) {
    __syncthreads();                       // Ks/Vt/Ps consumed
    *(uint4*)&Ks[krow][kseg * 16] = kr0;
    *(uint4*)&Ks[krow][kseg * 16 + 8] = kr1;
    *(uint4*)&Vt[krow][kseg * 16] = vr0;
    *(uint4*)&Vt[krow][kseg * 16 + 8] = vr1;
    __syncthreads();

    // bias for current tile (outstanding during QK), then prefetch t+1 K/V
    uint4 bb0 = *(const uint4*)(bptr + (size_t)t * 4096);
    uint4 bb1 = *(const uint4*)(bptr + (size_t)t * 4096 + 8);
    if (t < qt) {
      kr0 = *(const uint4*)(kptr + (size_t)(t + 1) * 4096);
      kr1 = *(const uint4*)(kptr + (size_t)(t + 1) * 4096 + 8);
      vr0 = *(const uint4*)(vptr + (size_t)(t + 1) * 64);
      vr1 = *(const uint4*)(vptr + (size_t)(t + 1) * 64 + 8);
    }

    // ---- S = (Q/8) K^T
    f32x4 s[4];
    #pragma unroll
    for (int nb = 0; nb < 4; ++nb) s[nb] = (f32x4)0.0f;
    #pragma unroll
    for (int ks = 0; ks < 2; ++ks) {
      bf16x8 aq = ks ? aq1 : aq0;
      #pragma unroll
      for (int nb = 0; nb < 4; ++nb) {
        bf16x8 bk = *(bf16x8*)&Ks[nb * 16 + l16][ks * 32 + quad * 8];
        s[nb] = __builtin_amdgcn_mfma_f32_16x16x32_bf16(aq, bk, s[nb], 0, 0, 0);
      }
    }

    // ---- p = exp(s + bias)  (bias holds -inf for masked) ; accumulate l
    #pragma unroll
    for (int nb = 0; nb < 4; ++nb) {
      #pragma unroll
      for (int r = 0; r < 4; ++r) {
        int v = nb * 4 + r;
        ushort_t bu = (v < 8) ? ((ushort_t*)&bb0)[v] : ((ushort_t*)&bb1)[v - 8];
        float p = __expf(s[nb][r] + bf2f(bu));
        ushort_t pu = f2bf(p);
        Ps[i0loc + r][nb * 16 + l16] = pu;
        ll[r] += bf2f(pu);                  // consistent with bf16 P used in PV
      }
    }

    // ---- O += P V  (wave-private Ps strip; same-wave write->read, no barrier)
    #pragma unroll
    for (int ks = 0; ks < 2; ++ks) {
      bf16x8 ap = *(bf16x8*)&Ps[w * 16 + l16][ks * 32 + quad * 8];
      #pragma unroll
      for (int nb = 0; nb < 4; ++nb) {
        bf16x8 bv = *(bf16x8*)&Vt[nb * 16 + l16][ks * 32 + quad * 8];
        o[nb] = __builtin_amdgcn_mfma_f32_16x16x32_bf16(ap, bv, o[nb], 0, 0, 0);
      }
    }
  }

  // ---- epilogue: reduce l across the 16 lanes once, store O/l (bf16)
  const int i0 = qt * 64 + i0loc;
  #pragma unroll
  for (int r = 0; r < 4; ++r) {
    float rs = ll[r];
    #pragma unroll
    for (int off = 1; off < 16; off <<= 1) rs += __shfl_xor(rs, off);
    float rl = 1.0f / rs;
    size_t ob = ((size_t)(b * S_LEN + i0 + r)) * 512 + h * KDIM;
    #pragma unroll
    for (int nb = 0; nb < 4; ++nb)
      Ob[ob + nb * 16 + l16] = f2bf(o[nb][r] * rl);
  }
}

// ---------------------------------------------------------------------------
extern "C" void kernel_launch(void* const* d_in, const int* in_sizes, int n_in,
                              void* d_out, int out_size, void* d_ws, size_t ws_size,
                              hipStream_t stream) {
  const float* src   = (const float*)d_in[0];
  const float* Wq    = (const float*)d_in[1];
  const float* Wk    = (const float*)d_in[2];
  const float* Wv    = (const float*)d_in[3];
  const float* c_raw = (const float*)d_in[4];
  const float* Lp    = (const float*)d_in[5];
  const float* w1    = (const float*)d_in[6];
  const float* b1    = (const float*)d_in[7];
  const float* W2    = (const float*)d_in[8];
  const float* b2    = (const float*)d_in[9];
  const float* w3    = (const float*)d_in[10];
  const float* b3    = (const float*)d_in[11];
  const float* Wo    = (const float*)d_in[12];
  float* outp = (float*)d_out;

  const size_t SRC_E = 4194304;   // 8*1024*512
  const size_t W_E   = 262144;    // 512*512
  const size_t QKV_E = 4194304;   // 64*1024*64
  ushort_t* srcb = (ushort_t*)d_ws;
  ushort_t* Wqb  = srcb + SRC_E;
  ushort_t* Wkb  = Wqb + W_E;
  ushort_t* Wvb  = Wkb + W_E;
  ushort_t* Wob  = Wvb + W_E;
  ushort_t* Qb   = Wob + W_E;
  ushort_t* Kb   = Qb + QKV_E;
  ushort_t* Vtb  = Kb + QKV_E;    // V transposed: [b,h,kd,s]
  ushort_t* Obb  = Vtb + QKV_E;
  ushort_t* biaspre = Obb + QKV_E;                 // 8*136*256*16
  float* numb  = (float*)(biaspre + (size_t)NHEAD * 136 * 256 * 16);
  float* rdenb = numb + NHEAD * S_LEN;
  float* gtabb = rdenb + NHEAD * S_LEN;

  hipLaunchKernelGGL(fire_tables, dim3(257, NHEAD), dim3(256), 0, stream,
                     c_raw, Lp, w1, b1, W2, b2, w3, b3, numb, rdenb, gtabb);
  hipLaunchKernelGGL(to_bf16, dim3(4096, 5), dim3(256), 0, stream,
                     src, Wq, Wk, Wv, Wo, srcb, Wqb, Wkb, Wvb, Wob);
  hipLaunchKernelGGL(fire_bias_pre, dim3(136, NHEAD), dim3(256), 0, stream,
                     numb, rdenb, gtabb, biaspre);
  hipLaunchKernelGGL(gemm_bf16, dim3(64, 4, 3), dim3(256), 0, stream,
                     srcb, Wqb, Wkb, Wvb, (void*)Qb, (void*)Kb, (void*)Vtb, 1);
  hipLaunchKernelGGL(fire_attn_mfma, dim3(1024), dim3(256), 0, stream,
                     Qb, Kb, Vtb, biaspre, Obb);
  hipLaunchKernelGGL(gemm_bf16, dim3(64, 4, 1), dim3(256), 0, stream,
                     Obb, Wob, Wob, Wob, (void*)outp, (void*)outp, (void*)outp, 0);
}

// Round 6
// 170.868 us; speedup vs baseline: 4.6018x; 1.0637x over previous
//
#include <hip/hip_runtime.h>
#include <math.h>

#define S_LEN 1024
#define NHEAD 8
#define BATCH 8
#define KDIM  64
#define HID   32
#define NT    2048
#define TRI(q) ((q) * ((q) + 1) / 2)
// key-order bit-shuffle: m=[nb1 nb0 q1 q0 r1 r0] -> key=[nb1 q1 q0 nb0 r1 r0]
#define PERM(m) (((m) & 0x20) | (((m) & 0x0C) << 1) | (((m) & 0x10) >> 2) | ((m) & 3))
// LDS column swizzle key per row (3 bits, conflict-free for both K(perm) and V reads)
#define SWZ(row) (((((row) >> 3) & 1) << 2) | ((row) & 3))

typedef __attribute__((ext_vector_type(8))) short bf16x8;
typedef __attribute__((ext_vector_type(4))) float f32x4;
typedef unsigned short ushort_t;

__device__ inline ushort_t f2bf(float f) {
  union { float f; unsigned u; } v; v.f = f;
  unsigned u = v.u;
  return (ushort_t)((u + 0x7FFFu + ((u >> 16) & 1u)) >> 16);
}
__device__ inline float bf2f(ushort_t u) {
  union { unsigned x; float f; } v; v.x = ((unsigned)u) << 16; return v.f;
}

// async global->LDS 16B: lane's LDS dest = lds_base + lane*16 (wave-uniform base)
__device__ inline void gl_lds16(const ushort_t* g, ushort_t* l) {
  __builtin_amdgcn_global_load_lds(
      (const __attribute__((address_space(1))) unsigned int*)g,
      (__attribute__((address_space(3))) unsigned int*)l, 16, 0, 0);
}

// ---------------------------------------------------------------------------
// Kernel 1: prep = to_bf16 (blocks 0..5119) + fire_tables (blocks 5120..7175).
// fire_tables: 32 lanes cooperate per table point (lane j = hidden dim j).
// ---------------------------------------------------------------------------
__global__ __launch_bounds__(256) void prep(
    const float* __restrict__ s, const float* __restrict__ wq,
    const float* __restrict__ wk, const float* __restrict__ wv,
    const float* __restrict__ wo,
    ushort_t* __restrict__ sb, ushort_t* __restrict__ wqb,
    ushort_t* __restrict__ wkb, ushort_t* __restrict__ wvb,
    ushort_t* __restrict__ wob,
    const float* __restrict__ c_raw, const float* __restrict__ Lp,
    const float* __restrict__ w1, const float* __restrict__ b1,
    const float* __restrict__ W2, const float* __restrict__ b2,
    const float* __restrict__ w3, const float* __restrict__ b3,
    float* __restrict__ num_g, float* __restrict__ rden_g,
    float* __restrict__ gtab_g) {
  __shared__ float h1s[8][33];
  const int bx = blockIdx.x;
  const int tid = threadIdx.x;
  if (bx < 5120) {
    const float* src; ushort_t* dst; int base; float scale = 1.0f;
    if (bx < 4096)      { src = s;  dst = sb;  base = bx; }
    else if (bx < 4352) { src = wq; dst = wqb; base = bx - 4096; scale = 0.125f; }
    else if (bx < 4608) { src = wk; dst = wkb; base = bx - 4352; }
    else if (bx < 4864) { src = wv; dst = wvb; base = bx - 4608; }
    else                { src = wo; dst = wob; base = bx - 4864; }
    const int i = (base * 256 + tid) * 4;
    float4 v = *(const float4*)&src[i];
    ushort4 o;
    o.x = f2bf(v.x * scale); o.y = f2bf(v.y * scale);
    o.z = f2bf(v.z * scale); o.w = f2bf(v.w * scale);
    *(ushort4*)&dst[i] = o;
  } else {
    const int idx = bx - 5120;
    const int h = idx / 257;
    const int xb = idx % 257;
    const float cr = c_raw[h];
    const float c = (cr > 20.f) ? cr : log1pf(expf(cr));
    const int gid = xb * 256 + tid;
    if (gid < S_LEN) {
      num_g[h * S_LEN + gid] = log1pf(c * (float)gid);
      rden_g[h * S_LEN + gid] = 1.0f / log1pf(c * fmaxf(Lp[h], (float)(gid + 1)));
    }
    const int pl = tid >> 5;             // point-local 0..7
    const int j = tid & 31;              // hidden dim
    const int pt = xb * 8 + pl;
    const float x = (float)pt * (1.0f / NT);
    float v = x * w1[h * HID + j] + b1[h * HID + j];
    h1s[pl][j] = 0.5f * v * (1.0f + erff(v * 0.70710678118f));
    __syncthreads();
    float sm = b2[h * HID + j];
    const float* w2r = W2 + ((size_t)(h * HID + j)) * HID;
    #pragma unroll
    for (int k = 0; k < HID; ++k) sm += w2r[k] * h1s[pl][k];
    float g = 0.5f * sm * (1.0f + erff(sm * 0.70710678118f));
    float y = w3[h * HID + j] * g;
    #pragma unroll
    for (int off = 1; off < 32; off <<= 1) y += __shfl_xor(y, off);
    if (j == 0 && pt <= NT) gtab_g[h * (NT + 1) + pt] = y + b3[h];
  }
}

// ---------------------------------------------------------------------------
// GEMM tile body: C = A(Mx512 bf16) * W^T (512x512 bf16, NxK). 128x128 tile,
// 2x2 wave grid (64x64/wave), BK=64, global_load_lds + XOR-swizzled LDS.
// mode 0: f32 row-major Mx512. mode 1: bf16 scatter [b,h,s,kd].
// mode 2: V^T bf16 [b,h,kd,s] via LDS transpose.
// ---------------------------------------------------------------------------
__device__ __forceinline__ void gemm_tile(
    ushort_t* sAB, const ushort_t* __restrict__ A, const ushort_t* __restrict__ Wp,
    void* __restrict__ outp, int mode, int m0, int n0, int tid) {
  ushort_t* sA = sAB;
  ushort_t* sB = sAB + 8192;
  const int lane = tid & 63, w = tid >> 6, quad = lane >> 4, l16 = lane & 15;
  const int wr = w >> 1, wc = w & 1;
  f32x4 acc[4][4];
  #pragma unroll
  for (int ia = 0; ia < 4; ++ia)
    #pragma unroll
    for (int ib = 0; ib < 4; ++ib) acc[ia][ib] = (f32x4)0.0f;

  const int r8 = lane >> 3;
  const int gc = (lane & 7) ^ r8;
  const int sw = l16 & 7;

  for (int kt = 0; kt < 512; kt += 64) {
    __syncthreads();
    #pragma unroll
    for (int j = 0; j < 4; ++j) {
      const int row = j * 32 + w * 8 + r8;
      gl_lds16(&A[(size_t)(m0 + row) * 512 + kt + gc * 8], &sA[(j * 32 + w * 8) * 64]);
      gl_lds16(&Wp[(size_t)(n0 + row) * 512 + kt + gc * 8], &sB[(j * 32 + w * 8) * 64]);
    }
    __syncthreads();
    #pragma unroll
    for (int ks = 0; ks < 2; ++ks) {
      const int off = ((ks * 4 + quad) ^ sw) * 8;
      bf16x8 af[4], bfr[4];
      #pragma unroll
      for (int i = 0; i < 4; ++i) {
        af[i] = *(bf16x8*)&sA[(wr * 64 + i * 16 + l16) * 64 + off];
        bfr[i] = *(bf16x8*)&sB[(wc * 64 + i * 16 + l16) * 64 + off];
      }
      #pragma unroll
      for (int ia = 0; ia < 4; ++ia)
        #pragma unroll
        for (int ib = 0; ib < 4; ++ib)
          acc[ia][ib] = __builtin_amdgcn_mfma_f32_16x16x32_bf16(af[ia], bfr[ib], acc[ia][ib], 0, 0, 0);
    }
  }

  if (mode == 2) {
    __syncthreads();
    #pragma unroll
    for (int ia = 0; ia < 4; ++ia)
      #pragma unroll
      for (int ib = 0; ib < 4; ++ib)
        #pragma unroll
        for (int r = 0; r < 4; ++r) {
          int nl = wc * 64 + ib * 16 + l16;
          int ml = wr * 64 + ia * 16 + quad * 4 + r;
          sAB[nl * 128 + (((ml >> 3) ^ (nl & 7)) * 8) + (ml & 7)] = f2bf(acc[ia][ib][r]);
        }
    __syncthreads();
    const int nl = tid >> 1, halfm = tid & 1;
    const int ng = n0 + nl, hh = ng >> 6, kd = ng & 63;
    const int bb = m0 >> 10, sbase = m0 & 1023;
    ushort_t* vout = (ushort_t*)outp + (((size_t)(bb * NHEAD + hh)) * KDIM + kd) * S_LEN;
    #pragma unroll
    for (int c2 = 0; c2 < 8; ++c2) {
      int mc = halfm * 8 + c2;
      bf16x8 vr = *(bf16x8*)&sAB[nl * 128 + ((mc ^ (nl & 7)) * 8)];
      *(bf16x8*)&vout[sbase + mc * 8] = vr;
    }
    return;
  }
  #pragma unroll
  for (int ia = 0; ia < 4; ++ia) {
    #pragma unroll
    for (int ib = 0; ib < 4; ++ib) {
      #pragma unroll
      for (int r = 0; r < 4; ++r) {
        int m = m0 + wr * 64 + ia * 16 + quad * 4 + r;
        int n = n0 + wc * 64 + ib * 16 + l16;
        float v = acc[ia][ib][r];
        if (mode == 1) {
          int bb = m >> 10, ss = m & 1023, hh = n >> 6, kd = n & 63;
          ((ushort_t*)outp)[(((size_t)(bb * NHEAD + hh)) * S_LEN + ss) * KDIM + kd] = f2bf(v);
        } else {
          ((float*)outp)[(size_t)m * 512 + n] = v;
        }
      }
    }
  }
}

// ---------------------------------------------------------------------------
// Kernel 2/4: gemm_bias. Blocks < nGemm: GEMM (z = blockIdx.x>>8 picks weight).
// Blocks >= nGemm: bias-pre (2 tiles per 256-thr block), fragment order for
// the transposed attention with PERM key order and causal -inf baked in.
// biaspre[h][TRI(qt)+t][tid2(128)][qg*16+nb*4+r] bf16; value maps to
// qrow i = qt*64 + w*32 + qg*16 + l16, key j = t*64 + PERM(nb*16+quad*4+r).
// ---------------------------------------------------------------------------
__global__ __launch_bounds__(256) void gemm_bias(
    const ushort_t* __restrict__ A,
    const ushort_t* __restrict__ W0, const ushort_t* __restrict__ W1,
    const ushort_t* __restrict__ W2w,
    void* __restrict__ out0, void* __restrict__ out1, void* __restrict__ out2,
    int scatter, int nGemm,
    const float* __restrict__ num_g, const float* __restrict__ rden_g,
    const float* __restrict__ gtab_g, ushort_t* __restrict__ biaspre) {
  __shared__ __align__(16) ushort_t sAB[16384];
  const int tid = threadIdx.x;
  if ((int)blockIdx.x < nGemm) {
    const int z = blockIdx.x >> 8;
    const int idx = blockIdx.x & 255;
    const int m0 = (idx & 63) * 128;
    const int n0 = (idx >> 6) * 128;
    const ushort_t* Wp = (z == 0) ? W0 : (z == 1) ? W1 : W2w;
    void* outp = (z == 0) ? out0 : (z == 1) ? out1 : out2;
    const int mode = scatter ? ((z == 2) ? 2 : 1) : 0;
    gemm_tile(sAB, A, Wp, outp, mode, m0, n0, tid);
  } else {
    const int idx = blockIdx.x - nGemm;      // 0..543
    const int h = idx / 68;
    const int pair = idx % 68;
    float* gtab_s = (float*)sAB;             // 2049
    float* num_s = gtab_s + 2052;            // 1024
    float* rden_s = num_s + 1024;            // [2][64]
    for (int i = tid; i <= NT; i += 256) gtab_s[i] = gtab_g[h * (NT + 1) + i];
    for (int i = tid; i < S_LEN; i += 256) num_s[i] = num_g[h * S_LEN + i];
    const int sub = tid >> 7, tid2 = tid & 127;
    const int tileIdx = pair * 2 + sub;
    int qt = 0;
    while (TRI(qt + 1) <= tileIdx) ++qt;
    const int t = tileIdx - TRI(qt);
    if (tid2 < 64) rden_s[sub * 64 + tid2] = rden_g[h * S_LEN + qt * 64 + tid2];
    __syncthreads();
    const int w = tid2 >> 6, lane = tid2 & 63, quad = lane >> 4, l16 = lane & 15;
    ushort_t vals[32];
    #pragma unroll
    for (int qg = 0; qg < 2; ++qg) {
      const int iloc = w * 32 + qg * 16 + l16;
      const int i = qt * 64 + iloc;
      const float rden = rden_s[sub * 64 + iloc];
      #pragma unroll
      for (int nb = 0; nb < 4; ++nb)
        #pragma unroll
        for (int r = 0; r < 4; ++r) {
          const int m = nb * 16 + quad * 4 + r;
          const int j = t * 64 + PERM(m);
          ushort_t out;
          if (j > i) {
            out = 0xFF80;  // bf16 -inf (causal)
          } else {
            const int d = i - j;
            float x = num_s[d] * rden;       // in [0,1)
            float tf = x * (float)NT;
            int it = (int)tf; it = it < (NT - 1) ? it : (NT - 1);
            float fr = tf - (float)it;
            float ga = gtab_s[it];
            out = f2bf(ga + (gtab_s[it + 1] - ga) * fr);
          }
          vals[qg * 16 + nb * 4 + r] = out;
        }
    }
    ushort_t* dst = &biaspre[((size_t)(h * 136 + tileIdx) * 128 + tid2) * 32];
    uint4 u[2];
    #pragma unroll
    for (int half = 0; half < 2; ++half) {
      #pragma unroll
      for (int v = 0; v < 8; ++v) ((ushort_t*)&u[0])[v] = vals[half * 16 + v];
      #pragma unroll
      for (int v = 0; v < 8; ++v) ((ushort_t*)&u[1])[v] = vals[half * 16 + 8 + v];
      *(uint4*)(dst + half * 16) = u[0];
      *(uint4*)(dst + half * 16 + 8) = u[1];
    }
  }
}

// ---------------------------------------------------------------------------
// Kernel 3: transposed MFMA causal flash attention. 1024 blocks x 128 thr
// (2 waves x 32 q-rows), one (qt, b, h) each; per-CU iteration count is
// exactly 34 under round-robin dispatch. S^T = K.Q^T with PERM'd key order;
// P^T fragments for O^T = V^T.P^T are register-local (no LDS round-trip).
// K/V staged via global_load_lds with source-side XOR swizzle.
// ---------------------------------------------------------------------------
__global__ __launch_bounds__(128) void fire_attn_mfma(
    const ushort_t* __restrict__ Qg, const ushort_t* __restrict__ Kg,
    const ushort_t* __restrict__ Vtg, const ushort_t* __restrict__ biaspre,
    ushort_t* __restrict__ Ob) {
  __shared__ __align__(16) ushort_t Ks[64 * 64];
  __shared__ __align__(16) ushort_t Vt[64 * 64];
  const int tid = threadIdx.x;
  const int lane = tid & 63, w = tid >> 6, quad = lane >> 4, l16 = lane & 15;
  const int g = blockIdx.x >> 6;
  const int qt = (g < 8) ? (15 - g) : (g - 8);
  const int bh = blockIdx.x & 63, h = bh & 7, b = bh >> 3;

  // Q fragments (B-operand layout == A layout: [l16][quad*8+j]); Q pre-scaled 1/8
  bf16x8 q[2][2];
  {
    const size_t qb = (size_t)bh * S_LEN + qt * 64 + w * 32;
    #pragma unroll
    for (int qg = 0; qg < 2; ++qg)
      #pragma unroll
      for (int ks = 0; ks < 2; ++ks)
        q[qg][ks] = *(const bf16x8*)&Qg[(qb + qg * 16 + l16) * KDIM + ks * 32 + quad * 8];
  }

  const size_t kb = (size_t)bh * S_LEN * KDIM;
  const ushort_t* bptr = &biaspre[((size_t)(h * 136 + TRI(qt)) * 128 + tid) * 32];
  const int srow8 = lane >> 3;   // staging row-within-group
  const int sc = lane & 7;       // staging chunk

  f32x4 o[2][4];
  float ll[2] = {0.f, 0.f};
  #pragma unroll
  for (int qg = 0; qg < 2; ++qg)
    #pragma unroll
    for (int nb = 0; nb < 4; ++nb) o[qg][nb] = (f32x4)0.0f;

  for (int t = 0; t <= qt; ++t) {
    __syncthreads();
    #pragma unroll
    for (int j = 0; j < 4; ++j) {
      const int row = (w * 4 + j) * 8 + srow8;
      const int cc = sc ^ SWZ(row);
      gl_lds16(&Kg[kb + (size_t)(t * 64 + row) * 64 + cc * 8], &Ks[(w * 4 + j) * 512]);
      gl_lds16(&Vtg[kb + (size_t)row * 1024 + t * 64 + cc * 8], &Vt[(w * 4 + j) * 512]);
    }
    __syncthreads();

    // bias (fragment order, -inf baked); in flight during QK
    uint4 bb0 = ((const uint4*)(bptr + (size_t)t * 4096))[0];
    uint4 bb1 = ((const uint4*)(bptr + (size_t)t * 4096))[1];
    uint4 bb2 = ((const uint4*)(bptr + (size_t)t * 4096))[2];
    uint4 bb3 = ((const uint4*)(bptr + (size_t)t * 4096))[3];

    // ---- S^T = K . Q^T  (keys in PERM order on the m-dim)
    f32x4 s[2][4];
    #pragma unroll
    for (int qg = 0; qg < 2; ++qg)
      #pragma unroll
      for (int nb = 0; nb < 4; ++nb) s[qg][nb] = (f32x4)0.0f;
    #pragma unroll
    for (int ks = 0; ks < 2; ++ks) {
      #pragma unroll
      for (int nb = 0; nb < 4; ++nb) {
        const int rk = PERM(nb * 16 + l16);
        bf16x8 ak = *(bf16x8*)&Ks[rk * 64 + (((ks * 4 + quad) ^ SWZ(rk)) * 8)];
        #pragma unroll
        for (int qg = 0; qg < 2; ++qg)
          s[qg][nb] = __builtin_amdgcn_mfma_f32_16x16x32_bf16(ak, q[qg][ks], s[qg][nb], 0, 0, 0);
      }
    }

    // ---- P = exp(S + bias); no-max softmax (|logit| small); l per-lane
    ushort_t eb[2][16];
    #pragma unroll
    for (int qg = 0; qg < 2; ++qg) {
      #pragma unroll
      for (int nb = 0; nb < 4; ++nb)
        #pragma unroll
        for (int r = 0; r < 4; ++r) {
          const int v = qg * 16 + nb * 4 + r;
          const uint4& bq = (v < 8) ? bb0 : (v < 16) ? bb1 : (v < 24) ? bb2 : bb3;
          ushort_t bu = ((const ushort_t*)&bq)[v & 7];
          float p = __expf(s[qg][nb][r] + bf2f(bu));
          ll[qg] += p;
          eb[qg][nb * 4 + r] = f2bf(p);
        }
    }

    // ---- O^T += V^T . P^T   (P^T B-frags are register-local thanks to PERM)
    #pragma unroll
    for (int ks = 0; ks < 2; ++ks) {
      bf16x8 pf[2];
      #pragma unroll
      for (int qg = 0; qg < 2; ++qg) {
        union { bf16x8 v; unsigned u[4]; } pk;
        pk.u[0] = (unsigned)eb[qg][(2 * ks) * 4 + 0] | ((unsigned)eb[qg][(2 * ks) * 4 + 1] << 16);
        pk.u[1] = (unsigned)eb[qg][(2 * ks) * 4 + 2] | ((unsigned)eb[qg][(2 * ks) * 4 + 3] << 16);
        pk.u[2] = (unsigned)eb[qg][(2 * ks + 1) * 4 + 0] | ((unsigned)eb[qg][(2 * ks + 1) * 4 + 1] << 16);
        pk.u[3] = (unsigned)eb[qg][(2 * ks + 1) * 4 + 2] | ((unsigned)eb[qg][(2 * ks + 1) * 4 + 3] << 16);
        pf[qg] = pk.v;
      }
      #pragma unroll
      for (int nb = 0; nb < 4; ++nb) {
        const int rv = nb * 16 + l16;
        bf16x8 av = *(bf16x8*)&Vt[rv * 64 + (((ks * 4 + quad) ^ SWZ(rv)) * 8)];
        #pragma unroll
        for (int qg = 0; qg < 2; ++qg)
          o[qg][nb] = __builtin_amdgcn_mfma_f32_16x16x32_bf16(av, pf[qg], o[qg][nb], 0, 0, 0);
      }
    }
  }

  // ---- epilogue: l reduced across quads (qrow = qg*16+l16 for all lane vals)
  #pragma unroll
  for (int qg = 0; qg < 2; ++qg) {
    float rs = ll[qg];
    rs += __shfl_xor(rs, 16);
    rs += __shfl_xor(rs, 32);
    const float rl = 1.0f / rs;
    const size_t ob = ((size_t)(b * S_LEN + qt * 64 + w * 32 + qg * 16 + l16)) * 512 + h * KDIM;
    #pragma unroll
    for (int nb = 0; nb < 4; ++nb) {
      ushort4 ov;
      ov.x = f2bf(o[qg][nb][0] * rl);
      ov.y = f2bf(o[qg][nb][1] * rl);
      ov.z = f2bf(o[qg][nb][2] * rl);
      ov.w = f2bf(o[qg][nb][3] * rl);
      *(ushort4*)&Ob[ob + nb * 16 + quad * 4] = ov;
    }
  }
}

// ---------------------------------------------------------------------------
extern "C" void kernel_launch(void* const* d_in, const int* in_sizes, int n_in,
                              void* d_out, int out_size, void* d_ws, size_t ws_size,
                              hipStream_t stream) {
  const float* src   = (const float*)d_in[0];
  const float* Wq    = (const float*)d_in[1];
  const float* Wk    = (const float*)d_in[2];
  const float* Wv    = (const float*)d_in[3];
  const float* c_raw = (const float*)d_in[4];
  const float* Lp    = (const float*)d_in[5];
  const float* w1    = (const float*)d_in[6];
  const float* b1    = (const float*)d_in[7];
  const float* W2    = (const float*)d_in[8];
  const float* b2    = (const float*)d_in[9];
  const float* w3    = (const float*)d_in[10];
  const float* b3    = (const float*)d_in[11];
  const float* Wo    = (const float*)d_in[12];
  float* outp = (float*)d_out;

  const size_t SRC_E = 4194304;   // 8*1024*512
  const size_t W_E   = 262144;    // 512*512
  const size_t QKV_E = 4194304;   // 64*1024*64
  ushort_t* srcb = (ushort_t*)d_ws;
  ushort_t* Wqb  = srcb + SRC_E;
  ushort_t* Wkb  = Wqb + W_E;
  ushort_t* Wvb  = Wkb + W_E;
  ushort_t* Wob  = Wvb + W_E;
  ushort_t* Qb   = Wob + W_E;
  ushort_t* Kb   = Qb + QKV_E;
  ushort_t* Vtb  = Kb + QKV_E;    // V transposed: [b,h,kd,s]
  ushort_t* Obb  = Vtb + QKV_E;
  ushort_t* biaspre = Obb + QKV_E;                 // 8*136*128*32 ushorts
  float* numb  = (float*)(biaspre + (size_t)NHEAD * 136 * 128 * 32);
  float* rdenb = numb + NHEAD * S_LEN;
  float* gtabb = rdenb + NHEAD * S_LEN;

  // 1) bf16 convert + FIRE tables (independent, merged)
  hipLaunchKernelGGL(prep, dim3(7176), dim3(256), 0, stream,
                     src, Wq, Wk, Wv, Wo, srcb, Wqb, Wkb, Wvb, Wob,
                     c_raw, Lp, w1, b1, W2, b2, w3, b3, numb, rdenb, gtabb);
  // 2) QKV GEMM (768 blocks) + bias-pre (544 blocks), merged
  hipLaunchKernelGGL(gemm_bias, dim3(1312), dim3(256), 0, stream,
                     srcb, Wqb, Wkb, Wvb, (void*)Qb, (void*)Kb, (void*)Vtb,
                     1, 768, numb, rdenb, gtabb, biaspre);
  // 3) attention
  hipLaunchKernelGGL(fire_attn_mfma, dim3(1024), dim3(128), 0, stream,
                     Qb, Kb, Vtb, biaspre, Obb);
  // 4) output projection (f32 out)
  hipLaunchKernelGGL(gemm_bias, dim3(256), dim3(256), 0, stream,
                     Obb, Wob, Wob, Wob, (void*)outp, (void*)outp, (void*)outp,
                     0, 256, numb, rdenb, gtabb, biaspre);
}